// Round 13
// baseline (1313.340 us; speedup 1.0000x reference)
//
#include <hip/hip_runtime.h>
#include <stdint.h>

// Problem constants
constexpr int NB = 4;      // batch
constexpr int NC = 256;    // channels
constexpr int HW = 64;     // spatial side
constexpr int NP = 4096;   // HW*HW
constexpr int NM = 8;      // matrices for Newton-Schulz: 2 feats x 4 batches
constexpr int NS_ITERS = 7;       // lam_scaled ~0.135 -> residual 4.4e-13 at 7 (fp32 floor 6e-8)
constexpr int NSLAB = 256;        // R13: 64 -> 256 (score quads: keep 1024 blocks)
constexpr int PSLAB = NP / NSLAB; // 16
constexpr int KSPLIT = 8;         // cov K-split
constexpr int KCHUNK = NP / KSPLIT; // 512
constexpr int NTILE8 = 36;        // upper-tri 32-tiles in 8x8 grid (NS symmetric)

// fp16 Markidis split (bf16 2-split caused argmax flips). Pre-scale by 512
// keeps lo out of fp16-subnormal range; uniform scaling is argmax-invariant
// for D, and is divided back out for cov.
constexpr float SPLIT_SCALE = 512.0f;
constexpr double COV_DESCALE = 1.0 / ((double)SPLIT_SCALE * (double)SPLIT_SCALE);

typedef __attribute__((ext_vector_type(8))) _Float16 h8v;  // 8 fp16 (4 VGPRs)
typedef __attribute__((ext_vector_type(4))) _Float16 h4v;  // 4 fp16 (8B store)
typedef __attribute__((ext_vector_type(4))) float f4v;     // MFMA acc
typedef float f4u __attribute__((ext_vector_type(4), aligned(4)));  // R13: dword-aligned vec4

// async global->LDS, 16B per lane; lds arg must be wave-uniform
#define GLD16(lds, g)                                                        \
  __builtin_amdgcn_global_load_lds(                                          \
      (const __attribute__((address_space(1))) void*)(g),                    \
      (__attribute__((address_space(3))) void*)(lds), 16, 0, 0)

// ---------------------------------------------------------------------------
// 1. fused mean + raw fp16 split: (src-mu)*512 -> fp16 hi/lo in [c][p]
__global__ __launch_bounds__(256) void meansplit_kernel(const float* __restrict__ content,
                                                        const float* __restrict__ style,
                                                        float* __restrict__ mean,
                                                        _Float16* __restrict__ Czh,
                                                        _Float16* __restrict__ Czl) {
  int id = blockIdx.x;              // [0, 2*NB*NC) == m*NC + c
  int feat = id / (NB * NC);
  int bc = id % (NB * NC);
  const float* src = (feat ? style : content) + (size_t)bc * NP;
  int tid = threadIdx.x;
  float s = 0.f;
  for (int i = tid; i < NP; i += 256) s += src[i];
  __shared__ float red[256];
  red[tid] = s;
  __syncthreads();
  for (int st = 128; st > 0; st >>= 1) {
    if (tid < st) red[tid] += red[tid + st];
    __syncthreads();
  }
  float mu = red[0] * (1.0f / NP);
  if (tid == 0) mean[id] = mu;
  _Float16* oh = Czh + (size_t)id * NP;
  _Float16* ol = Czl + (size_t)id * NP;
  for (int f4 = tid; f4 < NP / 4; f4 += 256) {
    float4 v = *(const float4*)&src[f4 * 4];
    float vv[4] = {v.x, v.y, v.z, v.w};
    h4v h, l;
#pragma unroll
    for (int q = 0; q < 4; q++) {
      float sv = (vv[q] - mu) * SPLIT_SCALE;
      _Float16 hh = (_Float16)sv;
      h[q] = hh;
      l[q] = (_Float16)(sv - (float)hh);
    }
    *(h4v*)&oh[f4 * 4] = h;
    *(h4v*)&ol[f4 * 4] = l;
  }
}

// ---------------------------------------------------------------------------
// 2. MFMA syrk cov: 64x64 upper-tri tiles, 4-term fp16 split, per-32-k fp64 fold
__global__ __launch_bounds__(256) void cov_mfma_kernel(const _Float16* __restrict__ Czh,
                                                       const _Float16* __restrict__ Czl,
                                                       double* __restrict__ pcov) {
  __shared__ _Float16 sAh[64 * 32], sAl[64 * 32], sBh[64 * 32], sBl[64 * 32];
  int m = blockIdx.z;
  int t = blockIdx.x, ti = 0, rem = t;
  while (rem >= 4 - ti) { rem -= 4 - ti; ti++; }
  int tj = ti + rem;
  int i0 = ti * 64, j0 = tj * 64;
  const _Float16* Ah = Czh + ((size_t)m * NC + i0) * NP;
  const _Float16* Al = Czl + ((size_t)m * NC + i0) * NP;
  const _Float16* Bh = Czh + ((size_t)m * NC + j0) * NP;
  const _Float16* Bl = Czl + ((size_t)m * NC + j0) * NP;
  int k0base = blockIdx.y * KCHUNK;
  int tid = threadIdx.x, lane = tid & 63;
  int mm = lane & 15, quad = lane >> 4;
  int w = tid >> 6, qr = w & 1, qc = w >> 1;
  double dacc[2][2][4] = {};
  for (int step = 0; step < KCHUNK / 32; step++) {
    int k0 = k0base + step * 32;
    __syncthreads();
    {
      int row = tid >> 2, koff = (tid & 3) * 8;
      int sbase = (tid & ~63) * 8;   // wave-uniform
      GLD16(&sAh[sbase], Ah + (size_t)row * NP + k0 + koff);
      GLD16(&sAl[sbase], Al + (size_t)row * NP + k0 + koff);
      GLD16(&sBh[sbase], Bh + (size_t)row * NP + k0 + koff);
      GLD16(&sBl[sbase], Bl + (size_t)row * NP + k0 + koff);
    }
    __syncthreads();   // drains vmcnt per barrier semantics
    h8v afh[2], afl[2], bfh[2], bfl[2];
#pragma unroll
    for (int tt = 0; tt < 2; tt++) {
      int ra = (qr * 32 + tt * 16 + mm) * 32 + quad * 8;
      afh[tt] = *(const h8v*)&sAh[ra];
      afl[tt] = *(const h8v*)&sAl[ra];
      int rb = (qc * 32 + tt * 16 + mm) * 32 + quad * 8;
      bfh[tt] = *(const h8v*)&sBh[rb];
      bfl[tt] = *(const h8v*)&sBl[rb];
    }
    f4v acc[2][2] = {};
#pragma unroll
    for (int tr = 0; tr < 2; tr++)
#pragma unroll
      for (int tc = 0; tc < 2; tc++) {
        acc[tr][tc] = __builtin_amdgcn_mfma_f32_16x16x32_f16(afh[tr], bfh[tc], acc[tr][tc], 0, 0, 0);
        acc[tr][tc] = __builtin_amdgcn_mfma_f32_16x16x32_f16(afh[tr], bfl[tc], acc[tr][tc], 0, 0, 0);
        acc[tr][tc] = __builtin_amdgcn_mfma_f32_16x16x32_f16(afl[tr], bfh[tc], acc[tr][tc], 0, 0, 0);
        acc[tr][tc] = __builtin_amdgcn_mfma_f32_16x16x32_f16(afl[tr], bfl[tc], acc[tr][tc], 0, 0, 0);
      }
#pragma unroll
    for (int tr = 0; tr < 2; tr++)
#pragma unroll
      for (int tc = 0; tc < 2; tc++)
#pragma unroll
        for (int r = 0; r < 4; r++) dacc[tr][tc][r] += (double)acc[tr][tc][r];
  }
  double* dst = pcov + ((size_t)blockIdx.y * NM + m) * NC * NC;
  // C/D layout: col = lane&15, row = quad*4 + reg  [verified mapping]
#pragma unroll
  for (int tr = 0; tr < 2; tr++)
#pragma unroll
    for (int tc = 0; tc < 2; tc++)
#pragma unroll
      for (int r = 0; r < 4; r++) {
        int row = i0 + qr * 32 + tr * 16 + quad * 4 + r;
        int col = j0 + qc * 32 + tc * 16 + mm;
        dst[(size_t)row * NC + col] = dacc[tr][tc][r];
      }
}

// 2b. sum K-split partials; mirror lower triangle from upper tiles; descale
__global__ __launch_bounds__(256) void cov_reduce_kernel(const double* __restrict__ pcov,
                                                         double* __restrict__ cov) {
  size_t idx = (size_t)blockIdx.x * 256 + threadIdx.x;  // [0, NM*NC*NC)
  int m = (int)(idx >> 16);
  int ij = (int)(idx & 65535);
  int i = ij >> 8, j = ij & 255;
  int src = ((i >> 6) <= (j >> 6)) ? ij : ((j << 8) | i);
  double s = 0;
  for (int k = 0; k < KSPLIT; k++)
    s += pcov[((size_t)k * NM + m) * 65536 + src];
  cov[idx] = s * COV_DESCALE;
}

// ---------------------------------------------------------------------------
// 3. Gershgorin bound (abs row sum, A symmetric); init Y = s*A, Z = I
__global__ __launch_bounds__(256) void bound_init_kernel(const double* __restrict__ cov,
                                                         double* __restrict__ Y,
                                                         double* __restrict__ Z,
                                                         double* __restrict__ scaleArr) {
  int m = blockIdx.x;
  const double* A = cov + (size_t)m * NC * NC;
  int t = threadIdx.x;
  double s = 0;
  for (int i = 0; i < NC; i++) s += fabs(A[(size_t)i * NC + t]);   // coalesced
  __shared__ double red[256];
  red[t] = s;
  __syncthreads();
  for (int st = 128; st > 0; st >>= 1) {
    if (t < st) red[t] = fmax(red[t], red[t + st]);
    __syncthreads();
  }
  double scale = 1.0 / red[0];     // lam_max <= max abs row sum (rigorous upper bound)
  if (t == 0) scaleArr[m] = scale;
  double* Ym = Y + (size_t)m * NC * NC;
  double* Zm = Z + (size_t)m * NC * NC;
  for (int idx = t; idx < NC * NC; idx += 256) {
    Ym[idx] = A[idx] * scale;
    Zm[idx] = ((idx / NC) == (idx % NC)) ? 1.0 : 0.0;
  }
}

// ---------------------------------------------------------------------------
// NS iterates are polynomials in symmetric A -> Y, Z, T, Y*T, T*Z all
// symmetric. Compute only the 36/64 upper-tri 32x32 tiles, mirror-write lower.

// 4a. T = Z * Y (fp64, upper-tri 32x32 tiles, 2x2 micro, mirrored writes)
__global__ __launch_bounds__(256) void ns_t_kernel(const double* __restrict__ Zin,
                                                   const double* __restrict__ Yin,
                                                   double* __restrict__ T) {
  int m = blockIdx.z;
  const double* Am = Zin + (size_t)m * NC * NC;
  const double* Bm = Yin + (size_t)m * NC * NC;
  double* Tm = T + (size_t)m * NC * NC;
  __shared__ double As[32][33];
  __shared__ double Bs[32][33];
  int tid = threadIdx.x, tx = tid & 15, ty = tid >> 4;
  int t = blockIdx.x, ti = 0, rem = t;     // unrank upper-tri tile (8x8 grid)
  while (rem >= 8 - ti) { rem -= 8 - ti; ti++; }
  int tj = ti + rem;
  int i0 = ti * 32, j0 = tj * 32;
  double a00 = 0, a01 = 0, a10 = 0, a11 = 0;
  for (int k0 = 0; k0 < NC; k0 += 32) {
    for (int idx = tid; idx < 1024; idx += 256) {
      int r = idx >> 5, cc = idx & 31;
      As[r][cc] = Am[(size_t)(i0 + r) * NC + k0 + cc];
      Bs[r][cc] = Bm[(size_t)(k0 + r) * NC + j0 + cc];
    }
    __syncthreads();
#pragma unroll
    for (int kk = 0; kk < 32; kk++) {
      double x0 = As[ty * 2][kk], x1 = As[ty * 2 + 1][kk];
      double y0 = Bs[kk][tx * 2], y1 = Bs[kk][tx * 2 + 1];
      a00 += x0 * y0; a01 += x0 * y1; a10 += x1 * y0; a11 += x1 * y1;
    }
    __syncthreads();
  }
  Tm[(size_t)(i0 + ty * 2) * NC + j0 + tx * 2] = a00;
  Tm[(size_t)(i0 + ty * 2) * NC + j0 + tx * 2 + 1] = a01;
  Tm[(size_t)(i0 + ty * 2 + 1) * NC + j0 + tx * 2] = a10;
  Tm[(size_t)(i0 + ty * 2 + 1) * NC + j0 + tx * 2 + 1] = a11;
  if (ti != tj) {   // mirror tile, coalesced via LDS transpose (reuse As)
    As[ty * 2][tx * 2] = a00;
    As[ty * 2][tx * 2 + 1] = a01;
    As[ty * 2 + 1][tx * 2] = a10;
    As[ty * 2 + 1][tx * 2 + 1] = a11;
    __syncthreads();
    for (int idx = tid; idx < 1024; idx += 256) {
      int r = idx >> 5, cc = idx & 31;
      Tm[(size_t)(j0 + r) * NC + i0 + cc] = As[cc][r];
    }
  }
}

// 4b. Yout = 1.5*Yin - 0.5*Yin*T ; Zout = 1.5*Zin - 0.5*T*Zin
__global__ __launch_bounds__(256) void ns_upd_kernel(const double* __restrict__ Yin,
                                                     const double* __restrict__ Zin,
                                                     const double* __restrict__ T,
                                                     double* __restrict__ Yout,
                                                     double* __restrict__ Zout) {
  int z = blockIdx.z;
  int m = z & 7, which = z >> 3;
  size_t off = (size_t)m * NC * NC;
  const double* Am = which == 0 ? (Yin + off) : (T + off);
  const double* Bm = which == 0 ? (T + off) : (Zin + off);
  const double* Sm = which == 0 ? (Yin + off) : (Zin + off);
  double* Om = which == 0 ? (Yout + off) : (Zout + off);
  __shared__ double As[32][33];
  __shared__ double Bs[32][33];
  int tid = threadIdx.x, tx = tid & 15, ty = tid >> 4;
  int t = blockIdx.x, ti = 0, rem = t;     // unrank upper-tri tile (8x8 grid)
  while (rem >= 8 - ti) { rem -= 8 - ti; ti++; }
  int tj = ti + rem;
  int i0 = ti * 32, j0 = tj * 32;
  double a00 = 0, a01 = 0, a10 = 0, a11 = 0;
  for (int k0 = 0; k0 < NC; k0 += 32) {
    for (int idx = tid; idx < 1024; idx += 256) {
      int r = idx >> 5, cc = idx & 31;
      As[r][cc] = Am[(size_t)(i0 + r) * NC + k0 + cc];
      Bs[r][cc] = Bm[(size_t)(k0 + r) * NC + j0 + cc];
    }
    __syncthreads();
#pragma unroll
    for (int kk = 0; kk < 32; kk++) {
      double x0 = As[ty * 2][kk], x1 = As[ty * 2 + 1][kk];
      double y0 = Bs[kk][tx * 2], y1 = Bs[kk][tx * 2 + 1];
      a00 += x0 * y0; a01 += x0 * y1; a10 += x1 * y0; a11 += x1 * y1;
    }
    __syncthreads();
  }
  int r0 = i0 + ty * 2, c0 = j0 + tx * 2;
  double o00 = 1.5 * Sm[(size_t)r0 * NC + c0] - 0.5 * a00;
  double o01 = 1.5 * Sm[(size_t)r0 * NC + c0 + 1] - 0.5 * a01;
  double o10 = 1.5 * Sm[(size_t)(r0 + 1) * NC + c0] - 0.5 * a10;
  double o11 = 1.5 * Sm[(size_t)(r0 + 1) * NC + c0 + 1] - 0.5 * a11;
  Om[(size_t)r0 * NC + c0] = o00;
  Om[(size_t)r0 * NC + c0 + 1] = o01;
  Om[(size_t)(r0 + 1) * NC + c0] = o10;
  Om[(size_t)(r0 + 1) * NC + c0 + 1] = o11;
  if (ti != tj) {   // mirror tile via LDS transpose (reuse As)
    As[ty * 2][tx * 2] = o00;
    As[ty * 2][tx * 2 + 1] = o01;
    As[ty * 2 + 1][tx * 2] = o10;
    As[ty * 2 + 1][tx * 2 + 1] = o11;
    __syncthreads();
    for (int idx = tid; idx < 1024; idx += 256) {
      int r = idx >> 5, cc = idx & 31;
      Om[(size_t)(j0 + r) * NC + i0 + cc] = As[cc][r];
    }
  }
}

// ---------------------------------------------------------------------------
// 5. finalize: inv_c = Z_c*sqrt(s), inv_s = Z_s*sqrt(s), sqr_s = Y_s/sqrt(s)  (fp32)
__global__ __launch_bounds__(256) void finalize_kernel(const double* __restrict__ Yf,
                                                       const double* __restrict__ Zf,
                                                       const double* __restrict__ scaleArr,
                                                       float* __restrict__ inv_c,
                                                       float* __restrict__ inv_s,
                                                       float* __restrict__ sqr_s) {
  int which = blockIdx.y;
  int idx = blockIdx.x * 256 + threadIdx.x;   // [0, NB*NC*NC)
  int b = idx >> 16;
  int ij = idx & 65535;
  if (which == 0) {
    double s = sqrt(scaleArr[b]);
    inv_c[idx] = (float)(Zf[(size_t)b * 65536 + ij] * s);
  } else if (which == 1) {
    double s = sqrt(scaleArr[4 + b]);
    inv_s[idx] = (float)(Zf[(size_t)(4 + b) * 65536 + ij] * s);
  } else {
    double s = sqrt(scaleArr[4 + b]);
    sqr_s[idx] = (float)(Yf[(size_t)(4 + b) * 65536 + ij] / s);
  }
}

// ---------------------------------------------------------------------------
// 6. R13 whitening: 256x (x) by 64c tile, 16x4 micro (64 FMA per 5 b128 reads;
//    was 32 per 3 — VALU-denser). Emits [p][c] directly; bit-identical k-order.
__global__ __launch_bounds__(256) void whiten_kernel(const float* __restrict__ content,
                                                     const float* __restrict__ style,
                                                     const float* __restrict__ mean,
                                                     const float* __restrict__ inv_c,
                                                     const float* __restrict__ inv_s,
                                                     float* __restrict__ ncwT,
                                                     float* __restrict__ nswT) {
  int z = blockIdx.z; int feat = z >> 2, b = z & 3;
  const float* src = (feat ? style : content) + (size_t)b * NC * NP;
  const float* mu = mean + (size_t)feat * NB * NC + b * NC;
  const float* M = (feat ? inv_s : inv_c) + (size_t)b * NC * NC;
  float* dst = (feat ? nswT : ncwT) + (size_t)b * NP * NC;   // [p][c]
  int x0 = blockIdx.x * 256, c0 = blockIdx.y * 64;
  __shared__ float Ms[32][68];    // [k][c], 272B rows
  __shared__ float Xs[32][264];   // [k][x], 1056B rows (66*16B aligned)
  int tid = threadIdx.x, tx = tid & 15, ty = tid >> 4;
  float acc[16][4] = {};   // [x_i][c_j]
  for (int k0 = 0; k0 < NC; k0 += 32) {
    for (int idx = tid; idx < 512; idx += 256) {
      int kk = idx >> 4, r4 = (idx & 15) * 4;
      *(float4*)&Ms[kk][r4] = *(const float4*)&M[(size_t)(k0 + kk) * NC + c0 + r4];
    }
    for (int idx = tid; idx < 2048; idx += 256) {
      int r = idx >> 6, c4 = (idx & 63) * 4;
      float4 v = *(const float4*)&src[(size_t)(k0 + r) * NP + x0 + c4];
      float mm = mu[k0 + r];
      v.x -= mm; v.y -= mm; v.z -= mm; v.w -= mm;
      *(float4*)&Xs[r][c4] = v;
    }
    __syncthreads();
#pragma unroll
    for (int kk = 0; kk < 32; kk++) {
      float4 xv4[4];
#pragma unroll
      for (int t4 = 0; t4 < 4; t4++) xv4[t4] = *(const float4*)&Xs[kk][ty * 16 + t4 * 4];
      float4 mv = *(const float4*)&Ms[kk][tx * 4];
      float xv[16] = {xv4[0].x, xv4[0].y, xv4[0].z, xv4[0].w,
                      xv4[1].x, xv4[1].y, xv4[1].z, xv4[1].w,
                      xv4[2].x, xv4[2].y, xv4[2].z, xv4[2].w,
                      xv4[3].x, xv4[3].y, xv4[3].z, xv4[3].w};
      float mm4[4] = {mv.x, mv.y, mv.z, mv.w};
#pragma unroll
      for (int i = 0; i < 16; i++)
#pragma unroll
        for (int j = 0; j < 4; j++) acc[i][j] += xv[i] * mm4[j];
    }
    __syncthreads();
  }
#pragma unroll
  for (int i = 0; i < 16; i++)
    *(float4*)&dst[(size_t)(x0 + ty * 16 + i) * NC + c0 + tx * 4] =
        make_float4(acc[i][0], acc[i][1], acc[i][2], acc[i][3]);
}

// ---------------------------------------------------------------------------
// 7. fused row-wise fp16 Markidis split + style ssq (one wave per row y)
__global__ __launch_bounds__(256) void split_kernel(const float* __restrict__ ncwT,
                                                    const float* __restrict__ nswT,
                                                    _Float16* __restrict__ BhiT,
                                                    _Float16* __restrict__ BloT,
                                                    _Float16* __restrict__ AhiT,
                                                    _Float16* __restrict__ AloT,
                                                    float* __restrict__ ssq) {
  int z = blockIdx.z; int feat = z >> 2, b = z & 3;
  int wave = threadIdx.x >> 6, lane = threadIdx.x & 63;
  int y = blockIdx.x * 4 + wave;
  const float* src = (feat ? nswT : ncwT) + ((size_t)b * NP + y) * NC;
  _Float16* oh = (feat ? AhiT : BhiT) + ((size_t)b * NP + y) * NC;
  _Float16* ol = (feat ? AloT : BloT) + ((size_t)b * NP + y) * NC;
  float4 v = *(const float4*)&src[lane * 4];
  float vv[4] = {v.x, v.y, v.z, v.w};
  h4v h, l;
#pragma unroll
  for (int q = 0; q < 4; q++) {
    float sv = vv[q] * SPLIT_SCALE;
    _Float16 hh = (_Float16)sv;          // v_cvt_f16_f32, RTN
    h[q] = hh;
    l[q] = (_Float16)(sv - (float)hh);
  }
  *(h4v*)&oh[lane * 4] = h;
  *(h4v*)&ol[lane * 4] = l;
  if (feat) {
    float s = vv[0] * vv[0] + vv[1] * vv[1] + vv[2] * vv[2] + vv[3] * vv[3];
#pragma unroll
    for (int off = 32; off > 0; off >>= 1) s += __shfl_down(s, off);
    if (lane == 0) ssq[b * NP + y] = s;
  }
}

__global__ __launch_bounds__(256) void rknorm_kernel(const float* __restrict__ ssq,
                                                     float* __restrict__ rk) {
  int idx = blockIdx.x * 256 + threadIdx.x;
  int b = idx >> 12, p = idx & 4095;
  int pi = p >> 6, pj = p & 63;
  float s = 0.f;
#pragma unroll
  for (int d = -1; d <= 1; d++)
#pragma unroll
    for (int e = -1; e <= 1; e++) {
      if ((unsigned)(pi + d) < 64u && (unsigned)(pj + e) < 64u)
        s += ssq[b * NP + (pi + d) * 64 + pj + e];
    }
  rk[idx] = 1.0f / sqrtf(s);
}

// ---------------------------------------------------------------------------
// 8. MFMA: D[p][x] = sum_c A[p][c]*B[x][c] via 3-term fp16 split (hh, hl, lh).
//    128x128 tile/block, 4 waves each 64x64 (4x4 of mfma_f32_16x16x32_f16),
//    BK=32, global_load_lds 16B staging.
__global__ __launch_bounds__(256) void dmat_kernel(const _Float16* __restrict__ AhiT,
                                                   const _Float16* __restrict__ AloT,
                                                   const _Float16* __restrict__ BhiT,
                                                   const _Float16* __restrict__ BloT,
                                                   float* __restrict__ D, int b) {
  __shared__ _Float16 sAh[128 * 32], sAl[128 * 32], sBh[128 * 32], sBl[128 * 32];
  const _Float16* Ah = AhiT + (size_t)b * NP * NC;
  const _Float16* Al = AloT + (size_t)b * NP * NC;
  const _Float16* Bh = BhiT + (size_t)b * NP * NC;
  const _Float16* Bl = BloT + (size_t)b * NP * NC;
  int p0 = blockIdx.x * 128, x0 = blockIdx.y * 128;
  int tid = threadIdx.x, lane = tid & 63;
  int m = lane & 15, quad = lane >> 4;
  int w = tid >> 6, qr = w & 1, qc = w >> 1;
  f4v acc[4][4] = {};
  for (int step = 0; step < NC / 32; step++) {
    int c0 = step * 32;
    __syncthreads();
#pragma unroll
    for (int i = 0; i < 2; i++) {
      int seg = i * 256 + tid;
      int row = seg >> 2, koff = (seg & 3) * 8;
      int sbase = (i * 256 + (tid & ~63)) * 8;   // wave-uniform
      GLD16(&sAh[sbase], Ah + (size_t)(p0 + row) * NC + c0 + koff);
      GLD16(&sAl[sbase], Al + (size_t)(p0 + row) * NC + c0 + koff);
      GLD16(&sBh[sbase], Bh + (size_t)(x0 + row) * NC + c0 + koff);
      GLD16(&sBl[sbase], Bl + (size_t)(x0 + row) * NC + c0 + koff);
    }
    __syncthreads();   // drains vmcnt (global_load_lds) per barrier semantics
    h8v afh[4], afl[4], bfh[4], bfl[4];
#pragma unroll
    for (int t = 0; t < 4; t++) {
      int ra = (qr * 64 + t * 16 + m) * 32 + quad * 8;
      afh[t] = *(const h8v*)&sAh[ra];
      afl[t] = *(const h8v*)&sAl[ra];
      int rb = (qc * 64 + t * 16 + m) * 32 + quad * 8;
      bfh[t] = *(const h8v*)&sBh[rb];
      bfl[t] = *(const h8v*)&sBl[rb];
    }
#pragma unroll
    for (int tr = 0; tr < 4; tr++)
#pragma unroll
      for (int tc = 0; tc < 4; tc++) {
        acc[tr][tc] = __builtin_amdgcn_mfma_f32_16x16x32_f16(afh[tr], bfh[tc], acc[tr][tc], 0, 0, 0);
        acc[tr][tc] = __builtin_amdgcn_mfma_f32_16x16x32_f16(afh[tr], bfl[tc], acc[tr][tc], 0, 0, 0);
        acc[tr][tc] = __builtin_amdgcn_mfma_f32_16x16x32_f16(afl[tr], bfh[tc], acc[tr][tc], 0, 0, 0);
      }
  }
  // C/D layout: col = lane&15, row = quad*4 + reg  [verified mapping]
#pragma unroll
  for (int tr = 0; tr < 4; tr++)
#pragma unroll
    for (int tc = 0; tc < 4; tc++)
#pragma unroll
      for (int r = 0; r < 4; r++) {
        int row = p0 + qr * 64 + tr * 16 + quad * 4 + r;
        int col = x0 + qc * 64 + tc * 16 + m;
        D[(size_t)row * NP + col] = acc[tr][tc][r];
      }
}

// ---------------------------------------------------------------------------
// 9. R13 score: each thread handles a quad of 4 consecutive x. Per (d,e) term
//    ONE dword-aligned float4 load covers all 4 outputs (9 loads/p for 4 x,
//    was 36). (pi+d, pj+e) masks are block-uniform scalar branches; only the
//    xj+e mask is per-element. Accumulation order (d,e ascending) and strict->
//    argmax preserved -> bit-identical results.
__global__ __launch_bounds__(256) void score_kernel(const float* __restrict__ D,
                                                    const float* __restrict__ rk,
                                                    float* __restrict__ pbest,
                                                    int* __restrict__ pidx, int b) {
  int xq = blockIdx.x * 256 + threadIdx.x;   // quad index [0, NP/4)
  int x4 = xq * 4;
  int slab = blockIdx.y;
  int xi = x4 >> 6, xj0 = x4 & 63;
  const float* rkb = rk + (size_t)b * NP;
  float best[4] = {-1e30f, -1e30f, -1e30f, -1e30f};
  int bi[4] = {0, 0, 0, 0};
  int p0 = slab * PSLAB;
  for (int p = p0; p < p0 + PSLAB; p++) {
    int pi = p >> 6, pj = p & 63;
    float acc[4] = {0.f, 0.f, 0.f, 0.f};
#pragma unroll
    for (int d = -1; d <= 1; d++) {
      if ((unsigned)(pi + d) >= 64u) continue;   // block-uniform
      bool xd = ((unsigned)(xi + d) < 64u);
#pragma unroll
      for (int e = -1; e <= 1; e++) {
        if ((unsigned)(pj + e) >= 64u) continue; // block-uniform
        int off = d * 64 + e;
        f4u v = *(const f4u*)&D[(size_t)(p + off) * NP + x4 + off];
#pragma unroll
        for (int i = 0; i < 4; i++) {
          bool ok = xd && ((unsigned)(xj0 + i + e) < 64u);
          acc[i] += ok ? v[i] : 0.f;
        }
      }
    }
    float r = rkb[p];
#pragma unroll
    for (int i = 0; i < 4; i++) {
      float s = acc[i] * r;
      if (s > best[i]) { best[i] = s; bi[i] = p; }
    }
  }
  *(float4*)&pbest[(size_t)slab * NP + x4] =
      make_float4(best[0], best[1], best[2], best[3]);
  *(int4*)&pidx[(size_t)slab * NP + x4] = make_int4(bi[0], bi[1], bi[2], bi[3]);
}

__global__ __launch_bounds__(256) void combine_kernel(const float* __restrict__ pbest,
                                                      const int* __restrict__ pidx,
                                                      int* __restrict__ bidx, int b) {
  int x = blockIdx.x * 256 + threadIdx.x;
  float best = pbest[x];
  int bi = pidx[x];
  for (int s = 1; s < NSLAB; s++) {
    float v = pbest[s * NP + x];
    if (v > best) { best = v; bi = pidx[s * NP + x]; }
  }
  bidx[b * NP + x] = bi;
}

// ---------------------------------------------------------------------------
// 11. gather-form overlap-add reassembly, divided by deconv norm (reads nswT [p][c])
__global__ __launch_bounds__(256) void reassemble_kernel(const float* __restrict__ nswT,
                                                         const int* __restrict__ bidx,
                                                         float* __restrict__ reass) {
  int by = blockIdx.x;       // b*NP + y
  int b = by >> 12, y = by & 4095;
  int yi = y >> 6, yj = y & 63;
  int t = threadIdx.x;       // channel
  float acc = 0.f;
#pragma unroll
  for (int oi = 0; oi < 3; oi++)
#pragma unroll
    for (int oj = 0; oj < 3; oj++) {
      int xi = yi + 1 - oi, xj = yj + 1 - oj;
      if ((unsigned)xi < 64u && (unsigned)xj < 64u) {
        int p = bidx[b * NP + xi * 64 + xj];
        int qi = (p >> 6) + oi - 1, qj = (p & 63) + oj - 1;
        if ((unsigned)qi < 64u && (unsigned)qj < 64u)
          acc += nswT[((size_t)b * NP + qi * 64 + qj) * NC + t];
      }
    }
  int cy = (yi == 0 || yi == 63) ? 2 : 3;
  int cx = (yj == 0 || yj == 63) ? 2 : 3;
  reass[((size_t)b * NP + y) * NC + t] = acc / (float)(cy * cx);
}

// ---------------------------------------------------------------------------
// 12. coloring: out[b][c][y] = sum_j sqr_s[b][c][j]*reass[b][y][j] + mean_s[b][c].
//     sqr_s symmetric -> As staged from rows (float4, conflict-free).
__global__ __launch_bounds__(256) void coloring_kernel(const float* __restrict__ sqr_s,
                                                       const float* __restrict__ reass,
                                                       const float* __restrict__ mean,
                                                       float* __restrict__ out) {
  int b = blockIdx.z;
  const float* A = sqr_s + (size_t)b * NC * NC;
  const float* Bm = reass + (size_t)b * NP * NC;
  const float* mu = mean + (size_t)NB * NC + b * NC;
  float* dst = out + (size_t)b * NC * NP;
  int c0 = blockIdx.x * 64, y0 = blockIdx.y * 64;
  __shared__ float As[32][68];   // [j][c], float4 rows
  __shared__ float Bs[32][66];   // [j][y], transposed scalar writes
  int tid = threadIdx.x, tx = tid & 15, ty = tid >> 4;
  float acc[4][4] = {};
  for (int k0 = 0; k0 < NC; k0 += 32) {
    for (int idx = tid; idx < 512; idx += 256) {
      int kk = idx >> 4, r4 = (idx & 15) * 4;   // A symmetric: row k, cols c
      *(float4*)&As[kk][r4] = *(const float4*)&A[(size_t)(k0 + kk) * NC + c0 + r4];
    }
    for (int idx = tid; idx < 2048; idx += 256) {
      int r = idx >> 5, kk = idx & 31;
      Bs[kk][r] = Bm[(size_t)(y0 + r) * NC + k0 + kk];
    }
    __syncthreads();
#pragma unroll
    for (int kk = 0; kk < 32; kk++) {
      float4 av = *(const float4*)&As[kk][ty * 4];
      float a[4] = {av.x, av.y, av.z, av.w};
      float bb[4];
      *(float2*)&bb[0] = *(const float2*)&Bs[kk][tx * 4];
      *(float2*)&bb[2] = *(const float2*)&Bs[kk][tx * 4 + 2];
#pragma unroll
      for (int i = 0; i < 4; i++)
#pragma unroll
        for (int j = 0; j < 4; j++) acc[i][j] += a[i] * bb[j];
    }
    __syncthreads();
  }
#pragma unroll
  for (int i = 0; i < 4; i++) {
    float m = mu[c0 + ty * 4 + i];
    float4 v = make_float4(acc[i][0] + m, acc[i][1] + m, acc[i][2] + m, acc[i][3] + m);
    *(float4*)&dst[(size_t)(c0 + ty * 4 + i) * NP + y0 + tx * 4] = v;
  }
}

// ---------------------------------------------------------------------------
extern "C" void kernel_launch(void* const* d_in, const int* in_sizes, int n_in,
                              void* d_out, int out_size, void* d_ws, size_t ws_size,
                              hipStream_t stream) {
  (void)in_sizes; (void)n_in; (void)out_size; (void)ws_size;
  const float* content = (const float*)d_in[0];
  const float* style = (const float*)d_in[1];
  float* out = (float*)d_out;

  // workspace carve-up (256B aligned)
  char* w = (char*)d_ws;
  auto alloc = [&](size_t bytes) -> void* {
    void* p = (void*)w;
    w += (bytes + 255) & ~(size_t)255;
    return p;
  };
  float* mean = (float*)alloc(2 * NB * NC * sizeof(float));
  double* pcov = (double*)alloc((size_t)KSPLIT * NM * NC * NC * sizeof(double));  // 32MB
  double* cov = (double*)alloc((size_t)NM * NC * NC * sizeof(double));
  double* Y0 = (double*)alloc((size_t)NM * NC * NC * sizeof(double));
  double* Z0 = (double*)alloc((size_t)NM * NC * NC * sizeof(double));
  double* Y1 = (double*)alloc((size_t)NM * NC * NC * sizeof(double));
  double* Z1 = (double*)alloc((size_t)NM * NC * NC * sizeof(double));
  double* T = (double*)alloc((size_t)NM * NC * NC * sizeof(double));
  double* scaleArr = (double*)alloc(NM * sizeof(double));
  float* inv_c = (float*)alloc((size_t)NB * NC * NC * sizeof(float));
  float* inv_s = (float*)alloc((size_t)NB * NC * NC * sizeof(float));
  float* sqr_s = (float*)alloc((size_t)NB * NC * NC * sizeof(float));
  float* ncwT = (float*)alloc((size_t)NB * NP * NC * sizeof(float));  // [p][c]
  float* nswT = (float*)alloc((size_t)NB * NP * NC * sizeof(float));  // [p][c]
  float* ssq = (float*)alloc((size_t)NB * NP * sizeof(float));
  float* rk = (float*)alloc((size_t)NB * NP * sizeof(float));
  float* pbest = (float*)alloc((size_t)NSLAB * NP * sizeof(float));   // 4MB
  int* pidx = (int*)alloc((size_t)NSLAB * NP * sizeof(int));          // 4MB
  int* bidx = (int*)alloc((size_t)NB * NP * sizeof(int));
  float* Dbuf = (float*)alloc((size_t)NP * NP * sizeof(float) + 4096);  // 64MB + shifted-f4 tail pad
  float* reass = Dbuf + (size_t)NB * NP * NC;          // [16MB, 32MB), used after score loop
  // raw fp16 split overlays Dbuf[0,32MB) — dead before dmat first writes Dbuf
  _Float16* Czh = (_Float16*)Dbuf;                       // 16MB: NM*NC*NP fp16
  _Float16* Czl = Czh + (size_t)NM * NC * NP;            // 16MB
  // whitened fp16 split arrays overlay pcov (dead after cov_reduce): 4 x 8MB
  _Float16* AhiT = (_Float16*)pcov;
  _Float16* AloT = AhiT + (size_t)NB * NP * NC;
  _Float16* BhiT = AloT + (size_t)NB * NP * NC;
  _Float16* BloT = BhiT + (size_t)NB * NP * NC;

  // 1-2: fused mean + raw split, then MFMA syrk cov
  meansplit_kernel<<<2 * NB * NC, 256, 0, stream>>>(content, style, mean, Czh, Czl);
  cov_mfma_kernel<<<dim3(10, KSPLIT, NM), 256, 0, stream>>>(Czh, Czl, pcov);
  cov_reduce_kernel<<<NM * NC * NC / 256, 256, 0, stream>>>(pcov, cov);

  // 3-4: Newton-Schulz inverse/forward sqrt in fp64 (Gershgorin-scaled,
  //      symmetric upper-tri tiles only)
  bound_init_kernel<<<NM, 256, 0, stream>>>(cov, Y0, Z0, scaleArr);
  double *Ya = Y0, *Za = Z0, *Yb = Y1, *Zb = Z1;
  for (int it = 0; it < NS_ITERS; it++) {
    ns_t_kernel<<<dim3(NTILE8, 1, NM), 256, 0, stream>>>(Za, Ya, T);
    ns_upd_kernel<<<dim3(NTILE8, 1, NM * 2), 256, 0, stream>>>(Ya, Za, T, Yb, Zb);
    double* tmp;
    tmp = Ya; Ya = Yb; Yb = tmp;
    tmp = Za; Za = Zb; Zb = tmp;
  }
  finalize_kernel<<<dim3(NB * NC * NC / 256, 3), 256, 0, stream>>>(Ya, Za, scaleArr,
                                                                   inv_c, inv_s, sqr_s);

  // 6: whiten both features, output [p][c] directly (256x64 tiles)
  whiten_kernel<<<dim3(NP / 256, NC / 64, 2 * NB), 256, 0, stream>>>(
      content, style, mean, inv_c, inv_s, ncwT, nswT);

  // 7: fused fp16 split + style ssq (row-wise), then knorm box
  split_kernel<<<dim3(NP / 4, 1, 2 * NB), 256, 0, stream>>>(ncwT, nswT,
                                                            BhiT, BloT, AhiT, AloT, ssq);
  rknorm_kernel<<<NB * NP / 256, 256, 0, stream>>>(ssq, rk);

  // 8-9: per batch: D = A B^T (MFMA fp16 3-term), then shifted-sum score + argmax
  for (int b = 0; b < NB; b++) {
    dmat_kernel<<<dim3(NP / 128, NP / 128), 256, 0, stream>>>(AhiT, AloT, BhiT, BloT, Dbuf, b);
    score_kernel<<<dim3(NP / 4 / 256, NSLAB), 256, 0, stream>>>(Dbuf, rk, pbest, pidx, b);
    combine_kernel<<<NP / 256, 256, 0, stream>>>(pbest, pidx, bidx, b);
  }

  // 11: reassembly (gather form) straight from nswT
  reassemble_kernel<<<NB * NP, 256, 0, stream>>>(nswT, bidx, reass);

  // 12: coloring straight into d_out (style_strength == 1.0)
  coloring_kernel<<<dim3(NC / 64, NP / 64, NB), 256, 0, stream>>>(sqr_s, reass, mean, out);
}

// Round 14
// 1146.770 us; speedup vs baseline: 1.1453x; 1.1453x over previous
//
#include <hip/hip_runtime.h>
#include <stdint.h>

// Problem constants
constexpr int NB = 4;      // batch
constexpr int NC = 256;    // channels
constexpr int HW = 64;     // spatial side
constexpr int NP = 4096;   // HW*HW
constexpr int NM = 8;      // matrices for Newton-Schulz: 2 feats x 4 batches
constexpr int NS_ITERS = 7;       // lam_scaled ~0.135 -> residual 4.4e-13 at 7 (fp32 floor 6e-8)
constexpr int NSLAB = 64;         // R14: reverted 256->64 (R13 combine 4x traffic regressed)
constexpr int PSLAB = NP / NSLAB; // 64
constexpr int KSPLIT = 8;         // cov K-split
constexpr int KCHUNK = NP / KSPLIT; // 512
constexpr int NTILE8 = 36;        // upper-tri 32-tiles in 8x8 grid (NS symmetric)

// fp16 Markidis split (bf16 2-split caused argmax flips). Pre-scale by 512
// keeps lo out of fp16-subnormal range; uniform scaling is argmax-invariant
// for D, and is divided back out for cov.
constexpr float SPLIT_SCALE = 512.0f;
constexpr double COV_DESCALE = 1.0 / ((double)SPLIT_SCALE * (double)SPLIT_SCALE);

typedef __attribute__((ext_vector_type(8))) _Float16 h8v;  // 8 fp16 (4 VGPRs)
typedef __attribute__((ext_vector_type(4))) _Float16 h4v;  // 4 fp16 (8B store)
typedef __attribute__((ext_vector_type(4))) float f4v;     // MFMA acc

// async global->LDS, 16B per lane; lds arg must be wave-uniform
#define GLD16(lds, g)                                                        \
  __builtin_amdgcn_global_load_lds(                                          \
      (const __attribute__((address_space(1))) void*)(g),                    \
      (__attribute__((address_space(3))) void*)(lds), 16, 0, 0)

// ---------------------------------------------------------------------------
// 1. fused mean + raw fp16 split: (src-mu)*512 -> fp16 hi/lo in [c][p]
__global__ __launch_bounds__(256) void meansplit_kernel(const float* __restrict__ content,
                                                        const float* __restrict__ style,
                                                        float* __restrict__ mean,
                                                        _Float16* __restrict__ Czh,
                                                        _Float16* __restrict__ Czl) {
  int id = blockIdx.x;              // [0, 2*NB*NC) == m*NC + c
  int feat = id / (NB * NC);
  int bc = id % (NB * NC);
  const float* src = (feat ? style : content) + (size_t)bc * NP;
  int tid = threadIdx.x;
  float s = 0.f;
  for (int i = tid; i < NP; i += 256) s += src[i];
  __shared__ float red[256];
  red[tid] = s;
  __syncthreads();
  for (int st = 128; st > 0; st >>= 1) {
    if (tid < st) red[tid] += red[tid + st];
    __syncthreads();
  }
  float mu = red[0] * (1.0f / NP);
  if (tid == 0) mean[id] = mu;
  _Float16* oh = Czh + (size_t)id * NP;
  _Float16* ol = Czl + (size_t)id * NP;
  for (int f4 = tid; f4 < NP / 4; f4 += 256) {
    float4 v = *(const float4*)&src[f4 * 4];
    float vv[4] = {v.x, v.y, v.z, v.w};
    h4v h, l;
#pragma unroll
    for (int q = 0; q < 4; q++) {
      float sv = (vv[q] - mu) * SPLIT_SCALE;
      _Float16 hh = (_Float16)sv;
      h[q] = hh;
      l[q] = (_Float16)(sv - (float)hh);
    }
    *(h4v*)&oh[f4 * 4] = h;
    *(h4v*)&ol[f4 * 4] = l;
  }
}

// ---------------------------------------------------------------------------
// 2. MFMA syrk cov: 64x64 upper-tri tiles, 4-term fp16 split, per-32-k fp64 fold
__global__ __launch_bounds__(256) void cov_mfma_kernel(const _Float16* __restrict__ Czh,
                                                       const _Float16* __restrict__ Czl,
                                                       double* __restrict__ pcov) {
  __shared__ _Float16 sAh[64 * 32], sAl[64 * 32], sBh[64 * 32], sBl[64 * 32];
  int m = blockIdx.z;
  int t = blockIdx.x, ti = 0, rem = t;
  while (rem >= 4 - ti) { rem -= 4 - ti; ti++; }
  int tj = ti + rem;
  int i0 = ti * 64, j0 = tj * 64;
  const _Float16* Ah = Czh + ((size_t)m * NC + i0) * NP;
  const _Float16* Al = Czl + ((size_t)m * NC + i0) * NP;
  const _Float16* Bh = Czh + ((size_t)m * NC + j0) * NP;
  const _Float16* Bl = Czl + ((size_t)m * NC + j0) * NP;
  int k0base = blockIdx.y * KCHUNK;
  int tid = threadIdx.x, lane = tid & 63;
  int mm = lane & 15, quad = lane >> 4;
  int w = tid >> 6, qr = w & 1, qc = w >> 1;
  double dacc[2][2][4] = {};
  for (int step = 0; step < KCHUNK / 32; step++) {
    int k0 = k0base + step * 32;
    __syncthreads();
    {
      int row = tid >> 2, koff = (tid & 3) * 8;
      int sbase = (tid & ~63) * 8;   // wave-uniform
      GLD16(&sAh[sbase], Ah + (size_t)row * NP + k0 + koff);
      GLD16(&sAl[sbase], Al + (size_t)row * NP + k0 + koff);
      GLD16(&sBh[sbase], Bh + (size_t)row * NP + k0 + koff);
      GLD16(&sBl[sbase], Bl + (size_t)row * NP + k0 + koff);
    }
    __syncthreads();   // drains vmcnt per barrier semantics
    h8v afh[2], afl[2], bfh[2], bfl[2];
#pragma unroll
    for (int tt = 0; tt < 2; tt++) {
      int ra = (qr * 32 + tt * 16 + mm) * 32 + quad * 8;
      afh[tt] = *(const h8v*)&sAh[ra];
      afl[tt] = *(const h8v*)&sAl[ra];
      int rb = (qc * 32 + tt * 16 + mm) * 32 + quad * 8;
      bfh[tt] = *(const h8v*)&sBh[rb];
      bfl[tt] = *(const h8v*)&sBl[rb];
    }
    f4v acc[2][2] = {};
#pragma unroll
    for (int tr = 0; tr < 2; tr++)
#pragma unroll
      for (int tc = 0; tc < 2; tc++) {
        acc[tr][tc] = __builtin_amdgcn_mfma_f32_16x16x32_f16(afh[tr], bfh[tc], acc[tr][tc], 0, 0, 0);
        acc[tr][tc] = __builtin_amdgcn_mfma_f32_16x16x32_f16(afh[tr], bfl[tc], acc[tr][tc], 0, 0, 0);
        acc[tr][tc] = __builtin_amdgcn_mfma_f32_16x16x32_f16(afl[tr], bfh[tc], acc[tr][tc], 0, 0, 0);
        acc[tr][tc] = __builtin_amdgcn_mfma_f32_16x16x32_f16(afl[tr], bfl[tc], acc[tr][tc], 0, 0, 0);
      }
#pragma unroll
    for (int tr = 0; tr < 2; tr++)
#pragma unroll
      for (int tc = 0; tc < 2; tc++)
#pragma unroll
        for (int r = 0; r < 4; r++) dacc[tr][tc][r] += (double)acc[tr][tc][r];
  }
  double* dst = pcov + ((size_t)blockIdx.y * NM + m) * NC * NC;
  // C/D layout: col = lane&15, row = quad*4 + reg  [verified mapping]
#pragma unroll
  for (int tr = 0; tr < 2; tr++)
#pragma unroll
    for (int tc = 0; tc < 2; tc++)
#pragma unroll
      for (int r = 0; r < 4; r++) {
        int row = i0 + qr * 32 + tr * 16 + quad * 4 + r;
        int col = j0 + qc * 32 + tc * 16 + mm;
        dst[(size_t)row * NC + col] = dacc[tr][tc][r];
      }
}

// 2b. sum K-split partials; mirror lower triangle from upper tiles; descale
__global__ __launch_bounds__(256) void cov_reduce_kernel(const double* __restrict__ pcov,
                                                         double* __restrict__ cov) {
  size_t idx = (size_t)blockIdx.x * 256 + threadIdx.x;  // [0, NM*NC*NC)
  int m = (int)(idx >> 16);
  int ij = (int)(idx & 65535);
  int i = ij >> 8, j = ij & 255;
  int src = ((i >> 6) <= (j >> 6)) ? ij : ((j << 8) | i);
  double s = 0;
  for (int k = 0; k < KSPLIT; k++)
    s += pcov[((size_t)k * NM + m) * 65536 + src];
  cov[idx] = s * COV_DESCALE;
}

// ---------------------------------------------------------------------------
// 3. Gershgorin bound (abs row sum, A symmetric); init Y = s*A, Z = I
__global__ __launch_bounds__(256) void bound_init_kernel(const double* __restrict__ cov,
                                                         double* __restrict__ Y,
                                                         double* __restrict__ Z,
                                                         double* __restrict__ scaleArr) {
  int m = blockIdx.x;
  const double* A = cov + (size_t)m * NC * NC;
  int t = threadIdx.x;
  double s = 0;
  for (int i = 0; i < NC; i++) s += fabs(A[(size_t)i * NC + t]);   // coalesced
  __shared__ double red[256];
  red[t] = s;
  __syncthreads();
  for (int st = 128; st > 0; st >>= 1) {
    if (t < st) red[t] = fmax(red[t], red[t + st]);
    __syncthreads();
  }
  double scale = 1.0 / red[0];     // lam_max <= max abs row sum (rigorous upper bound)
  if (t == 0) scaleArr[m] = scale;
  double* Ym = Y + (size_t)m * NC * NC;
  double* Zm = Z + (size_t)m * NC * NC;
  for (int idx = t; idx < NC * NC; idx += 256) {
    Ym[idx] = A[idx] * scale;
    Zm[idx] = ((idx / NC) == (idx % NC)) ? 1.0 : 0.0;
  }
}

// ---------------------------------------------------------------------------
// NS iterates are polynomials in symmetric A -> Y, Z, T, Y*T, T*Z all
// symmetric. Compute only the 36/64 upper-tri 32x32 tiles, mirror-write lower.

// 4a. T = Z * Y (fp64, upper-tri 32x32 tiles, 2x2 micro, mirrored writes)
__global__ __launch_bounds__(256) void ns_t_kernel(const double* __restrict__ Zin,
                                                   const double* __restrict__ Yin,
                                                   double* __restrict__ T) {
  int m = blockIdx.z;
  const double* Am = Zin + (size_t)m * NC * NC;
  const double* Bm = Yin + (size_t)m * NC * NC;
  double* Tm = T + (size_t)m * NC * NC;
  __shared__ double As[32][33];
  __shared__ double Bs[32][33];
  int tid = threadIdx.x, tx = tid & 15, ty = tid >> 4;
  int t = blockIdx.x, ti = 0, rem = t;     // unrank upper-tri tile (8x8 grid)
  while (rem >= 8 - ti) { rem -= 8 - ti; ti++; }
  int tj = ti + rem;
  int i0 = ti * 32, j0 = tj * 32;
  double a00 = 0, a01 = 0, a10 = 0, a11 = 0;
  for (int k0 = 0; k0 < NC; k0 += 32) {
    for (int idx = tid; idx < 1024; idx += 256) {
      int r = idx >> 5, cc = idx & 31;
      As[r][cc] = Am[(size_t)(i0 + r) * NC + k0 + cc];
      Bs[r][cc] = Bm[(size_t)(k0 + r) * NC + j0 + cc];
    }
    __syncthreads();
#pragma unroll
    for (int kk = 0; kk < 32; kk++) {
      double x0 = As[ty * 2][kk], x1 = As[ty * 2 + 1][kk];
      double y0 = Bs[kk][tx * 2], y1 = Bs[kk][tx * 2 + 1];
      a00 += x0 * y0; a01 += x0 * y1; a10 += x1 * y0; a11 += x1 * y1;
    }
    __syncthreads();
  }
  Tm[(size_t)(i0 + ty * 2) * NC + j0 + tx * 2] = a00;
  Tm[(size_t)(i0 + ty * 2) * NC + j0 + tx * 2 + 1] = a01;
  Tm[(size_t)(i0 + ty * 2 + 1) * NC + j0 + tx * 2] = a10;
  Tm[(size_t)(i0 + ty * 2 + 1) * NC + j0 + tx * 2 + 1] = a11;
  if (ti != tj) {   // mirror tile, coalesced via LDS transpose (reuse As)
    As[ty * 2][tx * 2] = a00;
    As[ty * 2][tx * 2 + 1] = a01;
    As[ty * 2 + 1][tx * 2] = a10;
    As[ty * 2 + 1][tx * 2 + 1] = a11;
    __syncthreads();
    for (int idx = tid; idx < 1024; idx += 256) {
      int r = idx >> 5, cc = idx & 31;
      Tm[(size_t)(j0 + r) * NC + i0 + cc] = As[cc][r];
    }
  }
}

// 4b. Yout = 1.5*Yin - 0.5*Yin*T ; Zout = 1.5*Zin - 0.5*T*Zin
__global__ __launch_bounds__(256) void ns_upd_kernel(const double* __restrict__ Yin,
                                                     const double* __restrict__ Zin,
                                                     const double* __restrict__ T,
                                                     double* __restrict__ Yout,
                                                     double* __restrict__ Zout) {
  int z = blockIdx.z;
  int m = z & 7, which = z >> 3;
  size_t off = (size_t)m * NC * NC;
  const double* Am = which == 0 ? (Yin + off) : (T + off);
  const double* Bm = which == 0 ? (T + off) : (Zin + off);
  const double* Sm = which == 0 ? (Yin + off) : (Zin + off);
  double* Om = which == 0 ? (Yout + off) : (Zout + off);
  __shared__ double As[32][33];
  __shared__ double Bs[32][33];
  int tid = threadIdx.x, tx = tid & 15, ty = tid >> 4;
  int t = blockIdx.x, ti = 0, rem = t;     // unrank upper-tri tile (8x8 grid)
  while (rem >= 8 - ti) { rem -= 8 - ti; ti++; }
  int tj = ti + rem;
  int i0 = ti * 32, j0 = tj * 32;
  double a00 = 0, a01 = 0, a10 = 0, a11 = 0;
  for (int k0 = 0; k0 < NC; k0 += 32) {
    for (int idx = tid; idx < 1024; idx += 256) {
      int r = idx >> 5, cc = idx & 31;
      As[r][cc] = Am[(size_t)(i0 + r) * NC + k0 + cc];
      Bs[r][cc] = Bm[(size_t)(k0 + r) * NC + j0 + cc];
    }
    __syncthreads();
#pragma unroll
    for (int kk = 0; kk < 32; kk++) {
      double x0 = As[ty * 2][kk], x1 = As[ty * 2 + 1][kk];
      double y0 = Bs[kk][tx * 2], y1 = Bs[kk][tx * 2 + 1];
      a00 += x0 * y0; a01 += x0 * y1; a10 += x1 * y0; a11 += x1 * y1;
    }
    __syncthreads();
  }
  int r0 = i0 + ty * 2, c0 = j0 + tx * 2;
  double o00 = 1.5 * Sm[(size_t)r0 * NC + c0] - 0.5 * a00;
  double o01 = 1.5 * Sm[(size_t)r0 * NC + c0 + 1] - 0.5 * a01;
  double o10 = 1.5 * Sm[(size_t)(r0 + 1) * NC + c0] - 0.5 * a10;
  double o11 = 1.5 * Sm[(size_t)(r0 + 1) * NC + c0 + 1] - 0.5 * a11;
  Om[(size_t)r0 * NC + c0] = o00;
  Om[(size_t)r0 * NC + c0 + 1] = o01;
  Om[(size_t)(r0 + 1) * NC + c0] = o10;
  Om[(size_t)(r0 + 1) * NC + c0 + 1] = o11;
  if (ti != tj) {   // mirror tile via LDS transpose (reuse As)
    As[ty * 2][tx * 2] = o00;
    As[ty * 2][tx * 2 + 1] = o01;
    As[ty * 2 + 1][tx * 2] = o10;
    As[ty * 2 + 1][tx * 2 + 1] = o11;
    __syncthreads();
    for (int idx = tid; idx < 1024; idx += 256) {
      int r = idx >> 5, cc = idx & 31;
      Om[(size_t)(j0 + r) * NC + i0 + cc] = As[cc][r];
    }
  }
}

// ---------------------------------------------------------------------------
// 5. finalize: inv_c = Z_c*sqrt(s), inv_s = Z_s*sqrt(s), sqr_s = Y_s/sqrt(s)  (fp32)
__global__ __launch_bounds__(256) void finalize_kernel(const double* __restrict__ Yf,
                                                       const double* __restrict__ Zf,
                                                       const double* __restrict__ scaleArr,
                                                       float* __restrict__ inv_c,
                                                       float* __restrict__ inv_s,
                                                       float* __restrict__ sqr_s) {
  int which = blockIdx.y;
  int idx = blockIdx.x * 256 + threadIdx.x;   // [0, NB*NC*NC)
  int b = idx >> 16;
  int ij = idx & 65535;
  if (which == 0) {
    double s = sqrt(scaleArr[b]);
    inv_c[idx] = (float)(Zf[(size_t)b * 65536 + ij] * s);
  } else if (which == 1) {
    double s = sqrt(scaleArr[4 + b]);
    inv_s[idx] = (float)(Zf[(size_t)(4 + b) * 65536 + ij] * s);
  } else {
    double s = sqrt(scaleArr[4 + b]);
    sqr_s[idx] = (float)(Yf[(size_t)(4 + b) * 65536 + ij] / s);
  }
}

// ---------------------------------------------------------------------------
// 6. whitening: outT[x][c] = sum_k (src[k][x]-mu[k]) * M[k][c]. Emits [p][c]
//    directly. M symmetric -> Ms[k][c] staged from M rows (float4, conflict-free).
//    128x64 tile, 8x4 micro (R14: reverted from 256-tile — occupancy cliff).
__global__ __launch_bounds__(256) void whiten_kernel(const float* __restrict__ content,
                                                     const float* __restrict__ style,
                                                     const float* __restrict__ mean,
                                                     const float* __restrict__ inv_c,
                                                     const float* __restrict__ inv_s,
                                                     float* __restrict__ ncwT,
                                                     float* __restrict__ nswT) {
  int z = blockIdx.z; int feat = z >> 2, b = z & 3;
  const float* src = (feat ? style : content) + (size_t)b * NC * NP;
  const float* mu = mean + (size_t)feat * NB * NC + b * NC;
  const float* M = (feat ? inv_s : inv_c) + (size_t)b * NC * NC;
  float* dst = (feat ? nswT : ncwT) + (size_t)b * NP * NC;   // [p][c]
  int x0 = blockIdx.x * 128, c0 = blockIdx.y * 64;
  __shared__ float Ms[32][68];    // [k][c]
  __shared__ float Xs[32][136];   // [k][x]
  int tid = threadIdx.x, tx = tid & 15, ty = tid >> 4;
  float acc[8][4] = {};   // [x_i][c_j]
  for (int k0 = 0; k0 < NC; k0 += 32) {
    for (int idx = tid; idx < 512; idx += 256) {
      int kk = idx >> 4, r4 = (idx & 15) * 4;
      *(float4*)&Ms[kk][r4] = *(const float4*)&M[(size_t)(k0 + kk) * NC + c0 + r4];
    }
    for (int idx = tid; idx < 1024; idx += 256) {
      int r = idx >> 5, c4 = (idx & 31) * 4;
      float4 v = *(const float4*)&src[(size_t)(k0 + r) * NP + x0 + c4];
      float mm = mu[k0 + r];
      v.x -= mm; v.y -= mm; v.z -= mm; v.w -= mm;
      *(float4*)&Xs[r][c4] = v;
    }
    __syncthreads();
#pragma unroll
    for (int kk = 0; kk < 32; kk++) {
      float4 xa = *(const float4*)&Xs[kk][ty * 8];
      float4 xb = *(const float4*)&Xs[kk][ty * 8 + 4];
      float4 mv = *(const float4*)&Ms[kk][tx * 4];
      float xv[8] = {xa.x, xa.y, xa.z, xa.w, xb.x, xb.y, xb.z, xb.w};
      float mm4[4] = {mv.x, mv.y, mv.z, mv.w};
#pragma unroll
      for (int i = 0; i < 8; i++)
#pragma unroll
        for (int j = 0; j < 4; j++) acc[i][j] += xv[i] * mm4[j];
    }
    __syncthreads();
  }
#pragma unroll
  for (int i = 0; i < 8; i++)
    *(float4*)&dst[(size_t)(x0 + ty * 8 + i) * NC + c0 + tx * 4] =
        make_float4(acc[i][0], acc[i][1], acc[i][2], acc[i][3]);
}

// ---------------------------------------------------------------------------
// 7. fused row-wise fp16 Markidis split + style ssq (one wave per row y)
__global__ __launch_bounds__(256) void split_kernel(const float* __restrict__ ncwT,
                                                    const float* __restrict__ nswT,
                                                    _Float16* __restrict__ BhiT,
                                                    _Float16* __restrict__ BloT,
                                                    _Float16* __restrict__ AhiT,
                                                    _Float16* __restrict__ AloT,
                                                    float* __restrict__ ssq) {
  int z = blockIdx.z; int feat = z >> 2, b = z & 3;
  int wave = threadIdx.x >> 6, lane = threadIdx.x & 63;
  int y = blockIdx.x * 4 + wave;
  const float* src = (feat ? nswT : ncwT) + ((size_t)b * NP + y) * NC;
  _Float16* oh = (feat ? AhiT : BhiT) + ((size_t)b * NP + y) * NC;
  _Float16* ol = (feat ? AloT : BloT) + ((size_t)b * NP + y) * NC;
  float4 v = *(const float4*)&src[lane * 4];
  float vv[4] = {v.x, v.y, v.z, v.w};
  h4v h, l;
#pragma unroll
  for (int q = 0; q < 4; q++) {
    float sv = vv[q] * SPLIT_SCALE;
    _Float16 hh = (_Float16)sv;          // v_cvt_f16_f32, RTN
    h[q] = hh;
    l[q] = (_Float16)(sv - (float)hh);
  }
  *(h4v*)&oh[lane * 4] = h;
  *(h4v*)&ol[lane * 4] = l;
  if (feat) {
    float s = vv[0] * vv[0] + vv[1] * vv[1] + vv[2] * vv[2] + vv[3] * vv[3];
#pragma unroll
    for (int off = 32; off > 0; off >>= 1) s += __shfl_down(s, off);
    if (lane == 0) ssq[b * NP + y] = s;
  }
}

__global__ __launch_bounds__(256) void rknorm_kernel(const float* __restrict__ ssq,
                                                     float* __restrict__ rk) {
  int idx = blockIdx.x * 256 + threadIdx.x;
  int b = idx >> 12, p = idx & 4095;
  int pi = p >> 6, pj = p & 63;
  float s = 0.f;
#pragma unroll
  for (int d = -1; d <= 1; d++)
#pragma unroll
    for (int e = -1; e <= 1; e++) {
      if ((unsigned)(pi + d) < 64u && (unsigned)(pj + e) < 64u)
        s += ssq[b * NP + (pi + d) * 64 + pj + e];
    }
  rk[idx] = 1.0f / sqrtf(s);
}

// ---------------------------------------------------------------------------
// 8. MFMA: D[p][x] = sum_c A[p][c]*B[x][c] via 3-term fp16 split (hh, hl, lh).
//    128x128 tile/block, 4 waves each 64x64 (4x4 of mfma_f32_16x16x32_f16),
//    BK=32, global_load_lds 16B staging.
__global__ __launch_bounds__(256) void dmat_kernel(const _Float16* __restrict__ AhiT,
                                                   const _Float16* __restrict__ AloT,
                                                   const _Float16* __restrict__ BhiT,
                                                   const _Float16* __restrict__ BloT,
                                                   float* __restrict__ D, int b) {
  __shared__ _Float16 sAh[128 * 32], sAl[128 * 32], sBh[128 * 32], sBl[128 * 32];
  const _Float16* Ah = AhiT + (size_t)b * NP * NC;
  const _Float16* Al = AloT + (size_t)b * NP * NC;
  const _Float16* Bh = BhiT + (size_t)b * NP * NC;
  const _Float16* Bl = BloT + (size_t)b * NP * NC;
  int p0 = blockIdx.x * 128, x0 = blockIdx.y * 128;
  int tid = threadIdx.x, lane = tid & 63;
  int m = lane & 15, quad = lane >> 4;
  int w = tid >> 6, qr = w & 1, qc = w >> 1;
  f4v acc[4][4] = {};
  for (int step = 0; step < NC / 32; step++) {
    int c0 = step * 32;
    __syncthreads();
#pragma unroll
    for (int i = 0; i < 2; i++) {
      int seg = i * 256 + tid;
      int row = seg >> 2, koff = (seg & 3) * 8;
      int sbase = (i * 256 + (tid & ~63)) * 8;   // wave-uniform
      GLD16(&sAh[sbase], Ah + (size_t)(p0 + row) * NC + c0 + koff);
      GLD16(&sAl[sbase], Al + (size_t)(p0 + row) * NC + c0 + koff);
      GLD16(&sBh[sbase], Bh + (size_t)(x0 + row) * NC + c0 + koff);
      GLD16(&sBl[sbase], Bl + (size_t)(x0 + row) * NC + c0 + koff);
    }
    __syncthreads();   // drains vmcnt (global_load_lds) per barrier semantics
    h8v afh[4], afl[4], bfh[4], bfl[4];
#pragma unroll
    for (int t = 0; t < 4; t++) {
      int ra = (qr * 64 + t * 16 + m) * 32 + quad * 8;
      afh[t] = *(const h8v*)&sAh[ra];
      afl[t] = *(const h8v*)&sAl[ra];
      int rb = (qc * 64 + t * 16 + m) * 32 + quad * 8;
      bfh[t] = *(const h8v*)&sBh[rb];
      bfl[t] = *(const h8v*)&sBl[rb];
    }
#pragma unroll
    for (int tr = 0; tr < 4; tr++)
#pragma unroll
      for (int tc = 0; tc < 4; tc++) {
        acc[tr][tc] = __builtin_amdgcn_mfma_f32_16x16x32_f16(afh[tr], bfh[tc], acc[tr][tc], 0, 0, 0);
        acc[tr][tc] = __builtin_amdgcn_mfma_f32_16x16x32_f16(afh[tr], bfl[tc], acc[tr][tc], 0, 0, 0);
        acc[tr][tc] = __builtin_amdgcn_mfma_f32_16x16x32_f16(afl[tr], bfh[tc], acc[tr][tc], 0, 0, 0);
      }
  }
  // C/D layout: col = lane&15, row = quad*4 + reg  [verified mapping]
#pragma unroll
  for (int tr = 0; tr < 4; tr++)
#pragma unroll
    for (int tc = 0; tc < 4; tc++)
#pragma unroll
      for (int r = 0; r < 4; r++) {
        int row = p0 + qr * 64 + tr * 16 + quad * 4 + r;
        int col = x0 + qc * 64 + tc * 16 + m;
        D[(size_t)row * NP + col] = acc[tr][tc][r];
      }
}

// ---------------------------------------------------------------------------
// 9. score[p][x] = (sum_{3x3 masked} D[p+off][x+off]) * rk[p]; partial argmax per p-slab
__global__ __launch_bounds__(256) void score_kernel(const float* __restrict__ D,
                                                    const float* __restrict__ rk,
                                                    float* __restrict__ pbest,
                                                    int* __restrict__ pidx, int b) {
  int x = blockIdx.x * 256 + threadIdx.x;
  int slab = blockIdx.y;
  int xi = x >> 6, xj = x & 63;
  const float* rkb = rk + (size_t)b * NP;
  bool xm[9];
#pragma unroll
  for (int q = 0; q < 9; q++) {
    int d = q / 3 - 1, e = q % 3 - 1;
    xm[q] = ((unsigned)(xi + d) < 64u) && ((unsigned)(xj + e) < 64u);
  }
  float best = -1e30f;
  int bi = 0;
  int p0 = slab * PSLAB;
  for (int p = p0; p < p0 + PSLAB; p++) {
    int pi = p >> 6, pj = p & 63;
    float acc = 0.f;
#pragma unroll
    for (int q = 0; q < 9; q++) {
      int d = q / 3 - 1, e = q % 3 - 1;
      int off = d * 64 + e;
      bool ok = xm[q] && ((unsigned)(pi + d) < 64u) && ((unsigned)(pj + e) < 64u);
      int row = ok ? p + off : p;
      int col = ok ? x + off : x;
      float t = D[(size_t)row * NP + col];
      acc += ok ? t : 0.f;
    }
    float s = acc * rkb[p];
    if (s > best) { best = s; bi = p; }
  }
  pbest[slab * NP + x] = best;
  pidx[slab * NP + x] = bi;
}

__global__ __launch_bounds__(256) void combine_kernel(const float* __restrict__ pbest,
                                                      const int* __restrict__ pidx,
                                                      int* __restrict__ bidx, int b) {
  int x = blockIdx.x * 256 + threadIdx.x;
  float best = pbest[x];
  int bi = pidx[x];
  for (int s = 1; s < NSLAB; s++) {
    float v = pbest[s * NP + x];
    if (v > best) { best = v; bi = pidx[s * NP + x]; }
  }
  bidx[b * NP + x] = bi;
}

// ---------------------------------------------------------------------------
// 11. gather-form overlap-add reassembly, divided by deconv norm (reads nswT [p][c])
__global__ __launch_bounds__(256) void reassemble_kernel(const float* __restrict__ nswT,
                                                         const int* __restrict__ bidx,
                                                         float* __restrict__ reass) {
  int by = blockIdx.x;       // b*NP + y
  int b = by >> 12, y = by & 4095;
  int yi = y >> 6, yj = y & 63;
  int t = threadIdx.x;       // channel
  float acc = 0.f;
#pragma unroll
  for (int oi = 0; oi < 3; oi++)
#pragma unroll
    for (int oj = 0; oj < 3; oj++) {
      int xi = yi + 1 - oi, xj = yj + 1 - oj;
      if ((unsigned)xi < 64u && (unsigned)xj < 64u) {
        int p = bidx[b * NP + xi * 64 + xj];
        int qi = (p >> 6) + oi - 1, qj = (p & 63) + oj - 1;
        if ((unsigned)qi < 64u && (unsigned)qj < 64u)
          acc += nswT[((size_t)b * NP + qi * 64 + qj) * NC + t];
      }
    }
  int cy = (yi == 0 || yi == 63) ? 2 : 3;
  int cx = (yj == 0 || yj == 63) ? 2 : 3;
  reass[((size_t)b * NP + y) * NC + t] = acc / (float)(cy * cx);
}

// ---------------------------------------------------------------------------
// 12. coloring: out[b][c][y] = sum_j sqr_s[b][c][j]*reass[b][y][j] + mean_s[b][c].
//     sqr_s symmetric -> As staged from rows (float4, conflict-free).
__global__ __launch_bounds__(256) void coloring_kernel(const float* __restrict__ sqr_s,
                                                       const float* __restrict__ reass,
                                                       const float* __restrict__ mean,
                                                       float* __restrict__ out) {
  int b = blockIdx.z;
  const float* A = sqr_s + (size_t)b * NC * NC;
  const float* Bm = reass + (size_t)b * NP * NC;
  const float* mu = mean + (size_t)NB * NC + b * NC;
  float* dst = out + (size_t)b * NC * NP;
  int c0 = blockIdx.x * 64, y0 = blockIdx.y * 64;
  __shared__ float As[32][68];   // [j][c], float4 rows
  __shared__ float Bs[32][66];   // [j][y], transposed scalar writes
  int tid = threadIdx.x, tx = tid & 15, ty = tid >> 4;
  float acc[4][4] = {};
  for (int k0 = 0; k0 < NC; k0 += 32) {
    for (int idx = tid; idx < 512; idx += 256) {
      int kk = idx >> 4, r4 = (idx & 15) * 4;   // A symmetric: row k, cols c
      *(float4*)&As[kk][r4] = *(const float4*)&A[(size_t)(k0 + kk) * NC + c0 + r4];
    }
    for (int idx = tid; idx < 2048; idx += 256) {
      int r = idx >> 5, kk = idx & 31;
      Bs[kk][r] = Bm[(size_t)(y0 + r) * NC + k0 + kk];
    }
    __syncthreads();
#pragma unroll
    for (int kk = 0; kk < 32; kk++) {
      float4 av = *(const float4*)&As[kk][ty * 4];
      float a[4] = {av.x, av.y, av.z, av.w};
      float bb[4];
      *(float2*)&bb[0] = *(const float2*)&Bs[kk][tx * 4];
      *(float2*)&bb[2] = *(const float2*)&Bs[kk][tx * 4 + 2];
#pragma unroll
      for (int i = 0; i < 4; i++)
#pragma unroll
        for (int j = 0; j < 4; j++) acc[i][j] += a[i] * bb[j];
    }
    __syncthreads();
  }
#pragma unroll
  for (int i = 0; i < 4; i++) {
    float m = mu[c0 + ty * 4 + i];
    float4 v = make_float4(acc[i][0] + m, acc[i][1] + m, acc[i][2] + m, acc[i][3] + m);
    *(float4*)&dst[(size_t)(c0 + ty * 4 + i) * NP + y0 + tx * 4] = v;
  }
}

// ---------------------------------------------------------------------------
extern "C" void kernel_launch(void* const* d_in, const int* in_sizes, int n_in,
                              void* d_out, int out_size, void* d_ws, size_t ws_size,
                              hipStream_t stream) {
  (void)in_sizes; (void)n_in; (void)out_size; (void)ws_size;
  const float* content = (const float*)d_in[0];
  const float* style = (const float*)d_in[1];
  float* out = (float*)d_out;

  // workspace carve-up (256B aligned)
  char* w = (char*)d_ws;
  auto alloc = [&](size_t bytes) -> void* {
    void* p = (void*)w;
    w += (bytes + 255) & ~(size_t)255;
    return p;
  };
  float* mean = (float*)alloc(2 * NB * NC * sizeof(float));
  double* pcov = (double*)alloc((size_t)KSPLIT * NM * NC * NC * sizeof(double));  // 32MB
  double* cov = (double*)alloc((size_t)NM * NC * NC * sizeof(double));
  double* Y0 = (double*)alloc((size_t)NM * NC * NC * sizeof(double));
  double* Z0 = (double*)alloc((size_t)NM * NC * NC * sizeof(double));
  double* Y1 = (double*)alloc((size_t)NM * NC * NC * sizeof(double));
  double* Z1 = (double*)alloc((size_t)NM * NC * NC * sizeof(double));
  double* T = (double*)alloc((size_t)NM * NC * NC * sizeof(double));
  double* scaleArr = (double*)alloc(NM * sizeof(double));
  float* inv_c = (float*)alloc((size_t)NB * NC * NC * sizeof(float));
  float* inv_s = (float*)alloc((size_t)NB * NC * NC * sizeof(float));
  float* sqr_s = (float*)alloc((size_t)NB * NC * NC * sizeof(float));
  float* ncwT = (float*)alloc((size_t)NB * NP * NC * sizeof(float));  // [p][c]
  float* nswT = (float*)alloc((size_t)NB * NP * NC * sizeof(float));  // [p][c]
  float* ssq = (float*)alloc((size_t)NB * NP * sizeof(float));
  float* rk = (float*)alloc((size_t)NB * NP * sizeof(float));
  float* pbest = (float*)alloc((size_t)NSLAB * NP * sizeof(float));
  int* pidx = (int*)alloc((size_t)NSLAB * NP * sizeof(int));
  int* bidx = (int*)alloc((size_t)NB * NP * sizeof(int));
  float* Dbuf = (float*)alloc((size_t)NP * NP * sizeof(float));  // 64MB, multi-overlaid:
  float* reass = Dbuf + (size_t)NB * NP * NC;          // [16MB, 32MB), used after score loop
  // raw fp16 split overlays Dbuf[0,32MB) — dead before dmat first writes Dbuf
  _Float16* Czh = (_Float16*)Dbuf;                       // 16MB: NM*NC*NP fp16
  _Float16* Czl = Czh + (size_t)NM * NC * NP;            // 16MB
  // whitened fp16 split arrays overlay pcov (dead after cov_reduce): 4 x 8MB
  _Float16* AhiT = (_Float16*)pcov;
  _Float16* AloT = AhiT + (size_t)NB * NP * NC;
  _Float16* BhiT = AloT + (size_t)NB * NP * NC;
  _Float16* BloT = BhiT + (size_t)NB * NP * NC;

  // 1-2: fused mean + raw split, then MFMA syrk cov
  meansplit_kernel<<<2 * NB * NC, 256, 0, stream>>>(content, style, mean, Czh, Czl);
  cov_mfma_kernel<<<dim3(10, KSPLIT, NM), 256, 0, stream>>>(Czh, Czl, pcov);
  cov_reduce_kernel<<<NM * NC * NC / 256, 256, 0, stream>>>(pcov, cov);

  // 3-4: Newton-Schulz inverse/forward sqrt in fp64 (Gershgorin-scaled,
  //      symmetric upper-tri tiles only)
  bound_init_kernel<<<NM, 256, 0, stream>>>(cov, Y0, Z0, scaleArr);
  double *Ya = Y0, *Za = Z0, *Yb = Y1, *Zb = Z1;
  for (int it = 0; it < NS_ITERS; it++) {
    ns_t_kernel<<<dim3(NTILE8, 1, NM), 256, 0, stream>>>(Za, Ya, T);
    ns_upd_kernel<<<dim3(NTILE8, 1, NM * 2), 256, 0, stream>>>(Ya, Za, T, Yb, Zb);
    double* tmp;
    tmp = Ya; Ya = Yb; Yb = tmp;
    tmp = Za; Za = Zb; Zb = tmp;
  }
  finalize_kernel<<<dim3(NB * NC * NC / 256, 3), 256, 0, stream>>>(Ya, Za, scaleArr,
                                                                   inv_c, inv_s, sqr_s);

  // 6: whiten both features, output [p][c] directly
  whiten_kernel<<<dim3(NP / 128, NC / 64, 2 * NB), 256, 0, stream>>>(
      content, style, mean, inv_c, inv_s, ncwT, nswT);

  // 7: fused fp16 split + style ssq (row-wise), then knorm box
  split_kernel<<<dim3(NP / 4, 1, 2 * NB), 256, 0, stream>>>(ncwT, nswT,
                                                            BhiT, BloT, AhiT, AloT, ssq);
  rknorm_kernel<<<NB * NP / 256, 256, 0, stream>>>(ssq, rk);

  // 8-9: per batch: D = A B^T (MFMA fp16 3-term), then shifted-sum score + argmax
  for (int b = 0; b < NB; b++) {
    dmat_kernel<<<dim3(NP / 128, NP / 128), 256, 0, stream>>>(AhiT, AloT, BhiT, BloT, Dbuf, b);
    score_kernel<<<dim3(NP / 256, NSLAB), 256, 0, stream>>>(Dbuf, rk, pbest, pidx, b);
    combine_kernel<<<NP / 256, 256, 0, stream>>>(pbest, pidx, bidx, b);
  }

  // 11: reassembly (gather form) straight from nswT
  reassemble_kernel<<<NB * NP, 256, 0, stream>>>(nswT, bidx, reass);

  // 12: coloring straight into d_out (style_strength == 1.0)
  coloring_kernel<<<dim3(NC / 64, NP / 64, NB), 256, 0, stream>>>(sqr_s, reass, mean, out);
}

// Round 15
// 1086.361 us; speedup vs baseline: 1.2089x; 1.0556x over previous
//
#include <hip/hip_runtime.h>
#include <stdint.h>

// Problem constants
constexpr int NB = 4;      // batch
constexpr int NC = 256;    // channels
constexpr int HW = 64;     // spatial side
constexpr int NP = 4096;   // HW*HW
constexpr int NM = 8;      // matrices for Newton-Schulz: 2 feats x 4 batches
constexpr int NS_ITERS = 7;       // lam_scaled ~0.135 -> residual 4.4e-13 at 7 (fp32 floor 6e-8)
constexpr int NSLAB = 128;        // R15: 64 -> 128 (combine gone -> more score parallelism is free)
constexpr int PSLAB = NP / NSLAB; // 32
constexpr int KSPLIT = 8;         // cov K-split
constexpr int KCHUNK = NP / KSPLIT; // 512
constexpr int NTILE8 = 36;        // upper-tri 32-tiles in 8x8 grid (NS symmetric)

// fp16 Markidis split (bf16 2-split caused argmax flips). Pre-scale by 512
// keeps lo out of fp16-subnormal range; uniform scaling is argmax-invariant
// for D, and is divided back out for cov.
constexpr float SPLIT_SCALE = 512.0f;
constexpr double COV_DESCALE = 1.0 / ((double)SPLIT_SCALE * (double)SPLIT_SCALE);

typedef __attribute__((ext_vector_type(8))) _Float16 h8v;  // 8 fp16 (4 VGPRs)
typedef __attribute__((ext_vector_type(4))) _Float16 h4v;  // 4 fp16 (8B store)
typedef __attribute__((ext_vector_type(4))) float f4v;     // MFMA acc

// async global->LDS, 16B per lane; lds arg must be wave-uniform
#define GLD16(lds, g)                                                        \
  __builtin_amdgcn_global_load_lds(                                          \
      (const __attribute__((address_space(1))) void*)(g),                    \
      (__attribute__((address_space(3))) void*)(lds), 16, 0, 0)

// monotone float -> sortable u32 (finite inputs): order(f) == order(sortable(f))
__device__ inline unsigned sortable_f32(float f) {
  unsigned u = __float_as_uint(f);
  return (u & 0x80000000u) ? ~u : (u | 0x80000000u);
}

// ---------------------------------------------------------------------------
// 1. fused mean + raw fp16 split: (src-mu)*512 -> fp16 hi/lo in [c][p]
__global__ __launch_bounds__(256) void meansplit_kernel(const float* __restrict__ content,
                                                        const float* __restrict__ style,
                                                        float* __restrict__ mean,
                                                        _Float16* __restrict__ Czh,
                                                        _Float16* __restrict__ Czl) {
  int id = blockIdx.x;              // [0, 2*NB*NC) == m*NC + c
  int feat = id / (NB * NC);
  int bc = id % (NB * NC);
  const float* src = (feat ? style : content) + (size_t)bc * NP;
  int tid = threadIdx.x;
  float s = 0.f;
  for (int i = tid; i < NP; i += 256) s += src[i];
  __shared__ float red[256];
  red[tid] = s;
  __syncthreads();
  for (int st = 128; st > 0; st >>= 1) {
    if (tid < st) red[tid] += red[tid + st];
    __syncthreads();
  }
  float mu = red[0] * (1.0f / NP);
  if (tid == 0) mean[id] = mu;
  _Float16* oh = Czh + (size_t)id * NP;
  _Float16* ol = Czl + (size_t)id * NP;
  for (int f4 = tid; f4 < NP / 4; f4 += 256) {
    float4 v = *(const float4*)&src[f4 * 4];
    float vv[4] = {v.x, v.y, v.z, v.w};
    h4v h, l;
#pragma unroll
    for (int q = 0; q < 4; q++) {
      float sv = (vv[q] - mu) * SPLIT_SCALE;
      _Float16 hh = (_Float16)sv;
      h[q] = hh;
      l[q] = (_Float16)(sv - (float)hh);
    }
    *(h4v*)&oh[f4 * 4] = h;
    *(h4v*)&ol[f4 * 4] = l;
  }
}

// ---------------------------------------------------------------------------
// 2. MFMA syrk cov: 64x64 upper-tri tiles, 4-term fp16 split, per-32-k fp64 fold
__global__ __launch_bounds__(256) void cov_mfma_kernel(const _Float16* __restrict__ Czh,
                                                       const _Float16* __restrict__ Czl,
                                                       double* __restrict__ pcov) {
  __shared__ _Float16 sAh[64 * 32], sAl[64 * 32], sBh[64 * 32], sBl[64 * 32];
  int m = blockIdx.z;
  int t = blockIdx.x, ti = 0, rem = t;
  while (rem >= 4 - ti) { rem -= 4 - ti; ti++; }
  int tj = ti + rem;
  int i0 = ti * 64, j0 = tj * 64;
  const _Float16* Ah = Czh + ((size_t)m * NC + i0) * NP;
  const _Float16* Al = Czl + ((size_t)m * NC + i0) * NP;
  const _Float16* Bh = Czh + ((size_t)m * NC + j0) * NP;
  const _Float16* Bl = Czl + ((size_t)m * NC + j0) * NP;
  int k0base = blockIdx.y * KCHUNK;
  int tid = threadIdx.x, lane = tid & 63;
  int mm = lane & 15, quad = lane >> 4;
  int w = tid >> 6, qr = w & 1, qc = w >> 1;
  double dacc[2][2][4] = {};
  for (int step = 0; step < KCHUNK / 32; step++) {
    int k0 = k0base + step * 32;
    __syncthreads();
    {
      int row = tid >> 2, koff = (tid & 3) * 8;
      int sbase = (tid & ~63) * 8;   // wave-uniform
      GLD16(&sAh[sbase], Ah + (size_t)row * NP + k0 + koff);
      GLD16(&sAl[sbase], Al + (size_t)row * NP + k0 + koff);
      GLD16(&sBh[sbase], Bh + (size_t)row * NP + k0 + koff);
      GLD16(&sBl[sbase], Bl + (size_t)row * NP + k0 + koff);
    }
    __syncthreads();   // drains vmcnt per barrier semantics
    h8v afh[2], afl[2], bfh[2], bfl[2];
#pragma unroll
    for (int tt = 0; tt < 2; tt++) {
      int ra = (qr * 32 + tt * 16 + mm) * 32 + quad * 8;
      afh[tt] = *(const h8v*)&sAh[ra];
      afl[tt] = *(const h8v*)&sAl[ra];
      int rb = (qc * 32 + tt * 16 + mm) * 32 + quad * 8;
      bfh[tt] = *(const h8v*)&sBh[rb];
      bfl[tt] = *(const h8v*)&sBl[rb];
    }
    f4v acc[2][2] = {};
#pragma unroll
    for (int tr = 0; tr < 2; tr++)
#pragma unroll
      for (int tc = 0; tc < 2; tc++) {
        acc[tr][tc] = __builtin_amdgcn_mfma_f32_16x16x32_f16(afh[tr], bfh[tc], acc[tr][tc], 0, 0, 0);
        acc[tr][tc] = __builtin_amdgcn_mfma_f32_16x16x32_f16(afh[tr], bfl[tc], acc[tr][tc], 0, 0, 0);
        acc[tr][tc] = __builtin_amdgcn_mfma_f32_16x16x32_f16(afl[tr], bfh[tc], acc[tr][tc], 0, 0, 0);
        acc[tr][tc] = __builtin_amdgcn_mfma_f32_16x16x32_f16(afl[tr], bfl[tc], acc[tr][tc], 0, 0, 0);
      }
#pragma unroll
    for (int tr = 0; tr < 2; tr++)
#pragma unroll
      for (int tc = 0; tc < 2; tc++)
#pragma unroll
        for (int r = 0; r < 4; r++) dacc[tr][tc][r] += (double)acc[tr][tc][r];
  }
  double* dst = pcov + ((size_t)blockIdx.y * NM + m) * NC * NC;
  // C/D layout: col = lane&15, row = quad*4 + reg  [verified mapping]
#pragma unroll
  for (int tr = 0; tr < 2; tr++)
#pragma unroll
    for (int tc = 0; tc < 2; tc++)
#pragma unroll
      for (int r = 0; r < 4; r++) {
        int row = i0 + qr * 32 + tr * 16 + quad * 4 + r;
        int col = j0 + qc * 32 + tc * 16 + mm;
        dst[(size_t)row * NC + col] = dacc[tr][tc][r];
      }
}

// 2b. sum K-split partials; mirror lower triangle from upper tiles; descale
__global__ __launch_bounds__(256) void cov_reduce_kernel(const double* __restrict__ pcov,
                                                         double* __restrict__ cov) {
  size_t idx = (size_t)blockIdx.x * 256 + threadIdx.x;  // [0, NM*NC*NC)
  int m = (int)(idx >> 16);
  int ij = (int)(idx & 65535);
  int i = ij >> 8, j = ij & 255;
  int src = ((i >> 6) <= (j >> 6)) ? ij : ((j << 8) | i);
  double s = 0;
  for (int k = 0; k < KSPLIT; k++)
    s += pcov[((size_t)k * NM + m) * 65536 + src];
  cov[idx] = s * COV_DESCALE;
}

// ---------------------------------------------------------------------------
// 3. Gershgorin bound (abs row sum, A symmetric); init Y = s*A, Z = I
__global__ __launch_bounds__(256) void bound_init_kernel(const double* __restrict__ cov,
                                                         double* __restrict__ Y,
                                                         double* __restrict__ Z,
                                                         double* __restrict__ scaleArr) {
  int m = blockIdx.x;
  const double* A = cov + (size_t)m * NC * NC;
  int t = threadIdx.x;
  double s = 0;
  for (int i = 0; i < NC; i++) s += fabs(A[(size_t)i * NC + t]);   // coalesced
  __shared__ double red[256];
  red[t] = s;
  __syncthreads();
  for (int st = 128; st > 0; st >>= 1) {
    if (t < st) red[t] = fmax(red[t], red[t + st]);
    __syncthreads();
  }
  double scale = 1.0 / red[0];     // lam_max <= max abs row sum (rigorous upper bound)
  if (t == 0) scaleArr[m] = scale;
  double* Ym = Y + (size_t)m * NC * NC;
  double* Zm = Z + (size_t)m * NC * NC;
  for (int idx = t; idx < NC * NC; idx += 256) {
    Ym[idx] = A[idx] * scale;
    Zm[idx] = ((idx / NC) == (idx % NC)) ? 1.0 : 0.0;
  }
}

// ---------------------------------------------------------------------------
// NS iterates are polynomials in symmetric A -> Y, Z, T, Y*T, T*Z all
// symmetric. Compute only the 36/64 upper-tri 32x32 tiles, mirror-write lower.

// 4a. T = Z * Y (fp64, upper-tri 32x32 tiles, 2x2 micro, mirrored writes)
__global__ __launch_bounds__(256) void ns_t_kernel(const double* __restrict__ Zin,
                                                   const double* __restrict__ Yin,
                                                   double* __restrict__ T) {
  int m = blockIdx.z;
  const double* Am = Zin + (size_t)m * NC * NC;
  const double* Bm = Yin + (size_t)m * NC * NC;
  double* Tm = T + (size_t)m * NC * NC;
  __shared__ double As[32][33];
  __shared__ double Bs[32][33];
  int tid = threadIdx.x, tx = tid & 15, ty = tid >> 4;
  int t = blockIdx.x, ti = 0, rem = t;     // unrank upper-tri tile (8x8 grid)
  while (rem >= 8 - ti) { rem -= 8 - ti; ti++; }
  int tj = ti + rem;
  int i0 = ti * 32, j0 = tj * 32;
  double a00 = 0, a01 = 0, a10 = 0, a11 = 0;
  for (int k0 = 0; k0 < NC; k0 += 32) {
    for (int idx = tid; idx < 1024; idx += 256) {
      int r = idx >> 5, cc = idx & 31;
      As[r][cc] = Am[(size_t)(i0 + r) * NC + k0 + cc];
      Bs[r][cc] = Bm[(size_t)(k0 + r) * NC + j0 + cc];
    }
    __syncthreads();
#pragma unroll
    for (int kk = 0; kk < 32; kk++) {
      double x0 = As[ty * 2][kk], x1 = As[ty * 2 + 1][kk];
      double y0 = Bs[kk][tx * 2], y1 = Bs[kk][tx * 2 + 1];
      a00 += x0 * y0; a01 += x0 * y1; a10 += x1 * y0; a11 += x1 * y1;
    }
    __syncthreads();
  }
  Tm[(size_t)(i0 + ty * 2) * NC + j0 + tx * 2] = a00;
  Tm[(size_t)(i0 + ty * 2) * NC + j0 + tx * 2 + 1] = a01;
  Tm[(size_t)(i0 + ty * 2 + 1) * NC + j0 + tx * 2] = a10;
  Tm[(size_t)(i0 + ty * 2 + 1) * NC + j0 + tx * 2 + 1] = a11;
  if (ti != tj) {   // mirror tile, coalesced via LDS transpose (reuse As)
    As[ty * 2][tx * 2] = a00;
    As[ty * 2][tx * 2 + 1] = a01;
    As[ty * 2 + 1][tx * 2] = a10;
    As[ty * 2 + 1][tx * 2 + 1] = a11;
    __syncthreads();
    for (int idx = tid; idx < 1024; idx += 256) {
      int r = idx >> 5, cc = idx & 31;
      Tm[(size_t)(j0 + r) * NC + i0 + cc] = As[cc][r];
    }
  }
}

// 4b. Yout = 1.5*Yin - 0.5*Yin*T ; Zout = 1.5*Zin - 0.5*T*Zin
__global__ __launch_bounds__(256) void ns_upd_kernel(const double* __restrict__ Yin,
                                                     const double* __restrict__ Zin,
                                                     const double* __restrict__ T,
                                                     double* __restrict__ Yout,
                                                     double* __restrict__ Zout) {
  int z = blockIdx.z;
  int m = z & 7, which = z >> 3;
  size_t off = (size_t)m * NC * NC;
  const double* Am = which == 0 ? (Yin + off) : (T + off);
  const double* Bm = which == 0 ? (T + off) : (Zin + off);
  const double* Sm = which == 0 ? (Yin + off) : (Zin + off);
  double* Om = which == 0 ? (Yout + off) : (Zout + off);
  __shared__ double As[32][33];
  __shared__ double Bs[32][33];
  int tid = threadIdx.x, tx = tid & 15, ty = tid >> 4;
  int t = blockIdx.x, ti = 0, rem = t;     // unrank upper-tri tile (8x8 grid)
  while (rem >= 8 - ti) { rem -= 8 - ti; ti++; }
  int tj = ti + rem;
  int i0 = ti * 32, j0 = tj * 32;
  double a00 = 0, a01 = 0, a10 = 0, a11 = 0;
  for (int k0 = 0; k0 < NC; k0 += 32) {
    for (int idx = tid; idx < 1024; idx += 256) {
      int r = idx >> 5, cc = idx & 31;
      As[r][cc] = Am[(size_t)(i0 + r) * NC + k0 + cc];
      Bs[r][cc] = Bm[(size_t)(k0 + r) * NC + j0 + cc];
    }
    __syncthreads();
#pragma unroll
    for (int kk = 0; kk < 32; kk++) {
      double x0 = As[ty * 2][kk], x1 = As[ty * 2 + 1][kk];
      double y0 = Bs[kk][tx * 2], y1 = Bs[kk][tx * 2 + 1];
      a00 += x0 * y0; a01 += x0 * y1; a10 += x1 * y0; a11 += x1 * y1;
    }
    __syncthreads();
  }
  int r0 = i0 + ty * 2, c0 = j0 + tx * 2;
  double o00 = 1.5 * Sm[(size_t)r0 * NC + c0] - 0.5 * a00;
  double o01 = 1.5 * Sm[(size_t)r0 * NC + c0 + 1] - 0.5 * a01;
  double o10 = 1.5 * Sm[(size_t)(r0 + 1) * NC + c0] - 0.5 * a10;
  double o11 = 1.5 * Sm[(size_t)(r0 + 1) * NC + c0 + 1] - 0.5 * a11;
  Om[(size_t)r0 * NC + c0] = o00;
  Om[(size_t)r0 * NC + c0 + 1] = o01;
  Om[(size_t)(r0 + 1) * NC + c0] = o10;
  Om[(size_t)(r0 + 1) * NC + c0 + 1] = o11;
  if (ti != tj) {   // mirror tile via LDS transpose (reuse As)
    As[ty * 2][tx * 2] = o00;
    As[ty * 2][tx * 2 + 1] = o01;
    As[ty * 2 + 1][tx * 2] = o10;
    As[ty * 2 + 1][tx * 2 + 1] = o11;
    __syncthreads();
    for (int idx = tid; idx < 1024; idx += 256) {
      int r = idx >> 5, cc = idx & 31;
      Om[(size_t)(j0 + r) * NC + i0 + cc] = As[cc][r];
    }
  }
}

// ---------------------------------------------------------------------------
// 5. finalize: inv_c = Z_c*sqrt(s), inv_s = Z_s*sqrt(s), sqr_s = Y_s/sqrt(s)  (fp32)
__global__ __launch_bounds__(256) void finalize_kernel(const double* __restrict__ Yf,
                                                       const double* __restrict__ Zf,
                                                       const double* __restrict__ scaleArr,
                                                       float* __restrict__ inv_c,
                                                       float* __restrict__ inv_s,
                                                       float* __restrict__ sqr_s) {
  int which = blockIdx.y;
  int idx = blockIdx.x * 256 + threadIdx.x;   // [0, NB*NC*NC)
  int b = idx >> 16;
  int ij = idx & 65535;
  if (which == 0) {
    double s = sqrt(scaleArr[b]);
    inv_c[idx] = (float)(Zf[(size_t)b * 65536 + ij] * s);
  } else if (which == 1) {
    double s = sqrt(scaleArr[4 + b]);
    inv_s[idx] = (float)(Zf[(size_t)(4 + b) * 65536 + ij] * s);
  } else {
    double s = sqrt(scaleArr[4 + b]);
    sqr_s[idx] = (float)(Yf[(size_t)(4 + b) * 65536 + ij] / s);
  }
}

// ---------------------------------------------------------------------------
// 6. whitening: outT[x][c] = sum_k (src[k][x]-mu[k]) * M[k][c]. Emits [p][c]
//    directly. M symmetric -> Ms[k][c] staged from M rows (float4, conflict-free).
//    128x64 tile, 8x4 micro.
__global__ __launch_bounds__(256) void whiten_kernel(const float* __restrict__ content,
                                                     const float* __restrict__ style,
                                                     const float* __restrict__ mean,
                                                     const float* __restrict__ inv_c,
                                                     const float* __restrict__ inv_s,
                                                     float* __restrict__ ncwT,
                                                     float* __restrict__ nswT) {
  int z = blockIdx.z; int feat = z >> 2, b = z & 3;
  const float* src = (feat ? style : content) + (size_t)b * NC * NP;
  const float* mu = mean + (size_t)feat * NB * NC + b * NC;
  const float* M = (feat ? inv_s : inv_c) + (size_t)b * NC * NC;
  float* dst = (feat ? nswT : ncwT) + (size_t)b * NP * NC;   // [p][c]
  int x0 = blockIdx.x * 128, c0 = blockIdx.y * 64;
  __shared__ float Ms[32][68];    // [k][c]
  __shared__ float Xs[32][136];   // [k][x]
  int tid = threadIdx.x, tx = tid & 15, ty = tid >> 4;
  float acc[8][4] = {};   // [x_i][c_j]
  for (int k0 = 0; k0 < NC; k0 += 32) {
    for (int idx = tid; idx < 512; idx += 256) {
      int kk = idx >> 4, r4 = (idx & 15) * 4;
      *(float4*)&Ms[kk][r4] = *(const float4*)&M[(size_t)(k0 + kk) * NC + c0 + r4];
    }
    for (int idx = tid; idx < 1024; idx += 256) {
      int r = idx >> 5, c4 = (idx & 31) * 4;
      float4 v = *(const float4*)&src[(size_t)(k0 + r) * NP + x0 + c4];
      float mm = mu[k0 + r];
      v.x -= mm; v.y -= mm; v.z -= mm; v.w -= mm;
      *(float4*)&Xs[r][c4] = v;
    }
    __syncthreads();
#pragma unroll
    for (int kk = 0; kk < 32; kk++) {
      float4 xa = *(const float4*)&Xs[kk][ty * 8];
      float4 xb = *(const float4*)&Xs[kk][ty * 8 + 4];
      float4 mv = *(const float4*)&Ms[kk][tx * 4];
      float xv[8] = {xa.x, xa.y, xa.z, xa.w, xb.x, xb.y, xb.z, xb.w};
      float mm4[4] = {mv.x, mv.y, mv.z, mv.w};
#pragma unroll
      for (int i = 0; i < 8; i++)
#pragma unroll
        for (int j = 0; j < 4; j++) acc[i][j] += xv[i] * mm4[j];
    }
    __syncthreads();
  }
#pragma unroll
  for (int i = 0; i < 8; i++)
    *(float4*)&dst[(size_t)(x0 + ty * 8 + i) * NC + c0 + tx * 4] =
        make_float4(acc[i][0], acc[i][1], acc[i][2], acc[i][3]);
}

// ---------------------------------------------------------------------------
// 7. fused row-wise fp16 Markidis split + style ssq (one wave per row y)
__global__ __launch_bounds__(256) void split_kernel(const float* __restrict__ ncwT,
                                                    const float* __restrict__ nswT,
                                                    _Float16* __restrict__ BhiT,
                                                    _Float16* __restrict__ BloT,
                                                    _Float16* __restrict__ AhiT,
                                                    _Float16* __restrict__ AloT,
                                                    float* __restrict__ ssq) {
  int z = blockIdx.z; int feat = z >> 2, b = z & 3;
  int wave = threadIdx.x >> 6, lane = threadIdx.x & 63;
  int y = blockIdx.x * 4 + wave;
  const float* src = (feat ? nswT : ncwT) + ((size_t)b * NP + y) * NC;
  _Float16* oh = (feat ? AhiT : BhiT) + ((size_t)b * NP + y) * NC;
  _Float16* ol = (feat ? AloT : BloT) + ((size_t)b * NP + y) * NC;
  float4 v = *(const float4*)&src[lane * 4];
  float vv[4] = {v.x, v.y, v.z, v.w};
  h4v h, l;
#pragma unroll
  for (int q = 0; q < 4; q++) {
    float sv = vv[q] * SPLIT_SCALE;
    _Float16 hh = (_Float16)sv;          // v_cvt_f16_f32, RTN
    h[q] = hh;
    l[q] = (_Float16)(sv - (float)hh);
  }
  *(h4v*)&oh[lane * 4] = h;
  *(h4v*)&ol[lane * 4] = l;
  if (feat) {
    float s = vv[0] * vv[0] + vv[1] * vv[1] + vv[2] * vv[2] + vv[3] * vv[3];
#pragma unroll
    for (int off = 32; off > 0; off >>= 1) s += __shfl_down(s, off);
    if (lane == 0) ssq[b * NP + y] = s;
  }
}

__global__ __launch_bounds__(256) void rknorm_kernel(const float* __restrict__ ssq,
                                                     float* __restrict__ rk) {
  int idx = blockIdx.x * 256 + threadIdx.x;
  int b = idx >> 12, p = idx & 4095;
  int pi = p >> 6, pj = p & 63;
  float s = 0.f;
#pragma unroll
  for (int d = -1; d <= 1; d++)
#pragma unroll
    for (int e = -1; e <= 1; e++) {
      if ((unsigned)(pi + d) < 64u && (unsigned)(pj + e) < 64u)
        s += ssq[b * NP + (pi + d) * 64 + pj + e];
    }
  rk[idx] = 1.0f / sqrtf(s);
}

// ---------------------------------------------------------------------------
// 8. MFMA: D[p][x] = sum_c A[p][c]*B[x][c] via 3-term fp16 split (hh, hl, lh).
//    128x128 tile/block, 4 waves each 64x64 (4x4 of mfma_f32_16x16x32_f16),
//    BK=32, global_load_lds 16B staging.
__global__ __launch_bounds__(256) void dmat_kernel(const _Float16* __restrict__ AhiT,
                                                   const _Float16* __restrict__ AloT,
                                                   const _Float16* __restrict__ BhiT,
                                                   const _Float16* __restrict__ BloT,
                                                   float* __restrict__ D, int b) {
  __shared__ _Float16 sAh[128 * 32], sAl[128 * 32], sBh[128 * 32], sBl[128 * 32];
  const _Float16* Ah = AhiT + (size_t)b * NP * NC;
  const _Float16* Al = AloT + (size_t)b * NP * NC;
  const _Float16* Bh = BhiT + (size_t)b * NP * NC;
  const _Float16* Bl = BloT + (size_t)b * NP * NC;
  int p0 = blockIdx.x * 128, x0 = blockIdx.y * 128;
  int tid = threadIdx.x, lane = tid & 63;
  int m = lane & 15, quad = lane >> 4;
  int w = tid >> 6, qr = w & 1, qc = w >> 1;
  f4v acc[4][4] = {};
  for (int step = 0; step < NC / 32; step++) {
    int c0 = step * 32;
    __syncthreads();
#pragma unroll
    for (int i = 0; i < 2; i++) {
      int seg = i * 256 + tid;
      int row = seg >> 2, koff = (seg & 3) * 8;
      int sbase = (i * 256 + (tid & ~63)) * 8;   // wave-uniform
      GLD16(&sAh[sbase], Ah + (size_t)(p0 + row) * NC + c0 + koff);
      GLD16(&sAl[sbase], Al + (size_t)(p0 + row) * NC + c0 + koff);
      GLD16(&sBh[sbase], Bh + (size_t)(x0 + row) * NC + c0 + koff);
      GLD16(&sBl[sbase], Bl + (size_t)(x0 + row) * NC + c0 + koff);
    }
    __syncthreads();   // drains vmcnt (global_load_lds) per barrier semantics
    h8v afh[4], afl[4], bfh[4], bfl[4];
#pragma unroll
    for (int t = 0; t < 4; t++) {
      int ra = (qr * 64 + t * 16 + m) * 32 + quad * 8;
      afh[t] = *(const h8v*)&sAh[ra];
      afl[t] = *(const h8v*)&sAl[ra];
      int rb = (qc * 64 + t * 16 + m) * 32 + quad * 8;
      bfh[t] = *(const h8v*)&sBh[rb];
      bfl[t] = *(const h8v*)&sBl[rb];
    }
#pragma unroll
    for (int tr = 0; tr < 4; tr++)
#pragma unroll
      for (int tc = 0; tc < 4; tc++) {
        acc[tr][tc] = __builtin_amdgcn_mfma_f32_16x16x32_f16(afh[tr], bfh[tc], acc[tr][tc], 0, 0, 0);
        acc[tr][tc] = __builtin_amdgcn_mfma_f32_16x16x32_f16(afh[tr], bfl[tc], acc[tr][tc], 0, 0, 0);
        acc[tr][tc] = __builtin_amdgcn_mfma_f32_16x16x32_f16(afl[tr], bfh[tc], acc[tr][tc], 0, 0, 0);
      }
  }
  // C/D layout: col = lane&15, row = quad*4 + reg  [verified mapping]
#pragma unroll
  for (int tr = 0; tr < 4; tr++)
#pragma unroll
    for (int tc = 0; tc < 4; tc++)
#pragma unroll
      for (int r = 0; r < 4; r++) {
        int row = p0 + qr * 64 + tr * 16 + quad * 4 + r;
        int col = x0 + qc * 64 + tc * 16 + m;
        D[(size_t)row * NP + col] = acc[tr][tc][r];
      }
}

// ---------------------------------------------------------------------------
// 9. R15 score: shifted-sum + slab-local argmax as before, then cross-slab
//    reduction via packed u64 atomicMax: key = (sortable(score)<<32) | ~p.
//    Among equal scores max(~p) = min(p) == jnp.argmax first-max tie rule.
//    Kills combine_kernel + pbest/pidx traffic.
__global__ __launch_bounds__(256) void score_kernel(const float* __restrict__ D,
                                                    const float* __restrict__ rk,
                                                    unsigned long long* __restrict__ packed,
                                                    int b) {
  int x = blockIdx.x * 256 + threadIdx.x;
  int slab = blockIdx.y;
  int xi = x >> 6, xj = x & 63;
  const float* rkb = rk + (size_t)b * NP;
  bool xm[9];
#pragma unroll
  for (int q = 0; q < 9; q++) {
    int d = q / 3 - 1, e = q % 3 - 1;
    xm[q] = ((unsigned)(xi + d) < 64u) && ((unsigned)(xj + e) < 64u);
  }
  float best = -1e30f;
  int bi = 0;
  int p0 = slab * PSLAB;
  for (int p = p0; p < p0 + PSLAB; p++) {
    int pi = p >> 6, pj = p & 63;
    float acc = 0.f;
#pragma unroll
    for (int q = 0; q < 9; q++) {
      int d = q / 3 - 1, e = q % 3 - 1;
      int off = d * 64 + e;
      bool ok = xm[q] && ((unsigned)(pi + d) < 64u) && ((unsigned)(pj + e) < 64u);
      int row = ok ? p + off : p;
      int col = ok ? x + off : x;
      float t = D[(size_t)row * NP + col];
      acc += ok ? t : 0.f;
    }
    float s = acc * rkb[p];
    if (s > best) { best = s; bi = p; }
  }
  unsigned long long key = ((unsigned long long)sortable_f32(best) << 32) |
                           (unsigned)(~(unsigned)bi);
  atomicMax(&packed[(size_t)b * NP + x], key);
}

// ---------------------------------------------------------------------------
// 11. gather-form overlap-add reassembly, divided by deconv norm (reads nswT [p][c]).
//     R15: unpacks argmax p from the packed u64 (p = ~lo & 4095).
__global__ __launch_bounds__(256) void reassemble_kernel(const float* __restrict__ nswT,
                                                         const unsigned long long* __restrict__ packed,
                                                         float* __restrict__ reass) {
  int by = blockIdx.x;       // b*NP + y
  int b = by >> 12, y = by & 4095;
  int yi = y >> 6, yj = y & 63;
  int t = threadIdx.x;       // channel
  float acc = 0.f;
#pragma unroll
  for (int oi = 0; oi < 3; oi++)
#pragma unroll
    for (int oj = 0; oj < 3; oj++) {
      int xi = yi + 1 - oi, xj = yj + 1 - oj;
      if ((unsigned)xi < 64u && (unsigned)xj < 64u) {
        unsigned long long v = packed[(size_t)b * NP + xi * 64 + xj];
        int p = (int)((~(unsigned)(v & 0xFFFFFFFFull)) & 4095u);
        int qi = (p >> 6) + oi - 1, qj = (p & 63) + oj - 1;
        if ((unsigned)qi < 64u && (unsigned)qj < 64u)
          acc += nswT[((size_t)b * NP + qi * 64 + qj) * NC + t];
      }
    }
  int cy = (yi == 0 || yi == 63) ? 2 : 3;
  int cx = (yj == 0 || yj == 63) ? 2 : 3;
  reass[((size_t)b * NP + y) * NC + t] = acc / (float)(cy * cx);
}

// ---------------------------------------------------------------------------
// 12. coloring: out[b][c][y] = sum_j sqr_s[b][c][j]*reass[b][y][j] + mean_s[b][c].
//     sqr_s symmetric -> As staged from rows (float4, conflict-free).
__global__ __launch_bounds__(256) void coloring_kernel(const float* __restrict__ sqr_s,
                                                       const float* __restrict__ reass,
                                                       const float* __restrict__ mean,
                                                       float* __restrict__ out) {
  int b = blockIdx.z;
  const float* A = sqr_s + (size_t)b * NC * NC;
  const float* Bm = reass + (size_t)b * NP * NC;
  const float* mu = mean + (size_t)NB * NC + b * NC;
  float* dst = out + (size_t)b * NC * NP;
  int c0 = blockIdx.x * 64, y0 = blockIdx.y * 64;
  __shared__ float As[32][68];   // [j][c], float4 rows
  __shared__ float Bs[32][66];   // [j][y], transposed scalar writes
  int tid = threadIdx.x, tx = tid & 15, ty = tid >> 4;
  float acc[4][4] = {};
  for (int k0 = 0; k0 < NC; k0 += 32) {
    for (int idx = tid; idx < 512; idx += 256) {
      int kk = idx >> 4, r4 = (idx & 15) * 4;   // A symmetric: row k, cols c
      *(float4*)&As[kk][r4] = *(const float4*)&A[(size_t)(k0 + kk) * NC + c0 + r4];
    }
    for (int idx = tid; idx < 2048; idx += 256) {
      int r = idx >> 5, kk = idx & 31;
      Bs[kk][r] = Bm[(size_t)(y0 + r) * NC + k0 + kk];
    }
    __syncthreads();
#pragma unroll
    for (int kk = 0; kk < 32; kk++) {
      float4 av = *(const float4*)&As[kk][ty * 4];
      float a[4] = {av.x, av.y, av.z, av.w};
      float bb[4];
      *(float2*)&bb[0] = *(const float2*)&Bs[kk][tx * 4];
      *(float2*)&bb[2] = *(const float2*)&Bs[kk][tx * 4 + 2];
#pragma unroll
      for (int i = 0; i < 4; i++)
#pragma unroll
        for (int j = 0; j < 4; j++) acc[i][j] += a[i] * bb[j];
    }
    __syncthreads();
  }
#pragma unroll
  for (int i = 0; i < 4; i++) {
    float m = mu[c0 + ty * 4 + i];
    float4 v = make_float4(acc[i][0] + m, acc[i][1] + m, acc[i][2] + m, acc[i][3] + m);
    *(float4*)&dst[(size_t)(c0 + ty * 4 + i) * NP + y0 + tx * 4] = v;
  }
}

// ---------------------------------------------------------------------------
extern "C" void kernel_launch(void* const* d_in, const int* in_sizes, int n_in,
                              void* d_out, int out_size, void* d_ws, size_t ws_size,
                              hipStream_t stream) {
  (void)in_sizes; (void)n_in; (void)out_size; (void)ws_size;
  const float* content = (const float*)d_in[0];
  const float* style = (const float*)d_in[1];
  float* out = (float*)d_out;

  // workspace carve-up (256B aligned)
  char* w = (char*)d_ws;
  auto alloc = [&](size_t bytes) -> void* {
    void* p = (void*)w;
    w += (bytes + 255) & ~(size_t)255;
    return p;
  };
  float* mean = (float*)alloc(2 * NB * NC * sizeof(float));
  double* pcov = (double*)alloc((size_t)KSPLIT * NM * NC * NC * sizeof(double));  // 32MB
  double* cov = (double*)alloc((size_t)NM * NC * NC * sizeof(double));
  double* Y0 = (double*)alloc((size_t)NM * NC * NC * sizeof(double));
  double* Z0 = (double*)alloc((size_t)NM * NC * NC * sizeof(double));
  double* Y1 = (double*)alloc((size_t)NM * NC * NC * sizeof(double));
  double* Z1 = (double*)alloc((size_t)NM * NC * NC * sizeof(double));
  double* T = (double*)alloc((size_t)NM * NC * NC * sizeof(double));
  double* scaleArr = (double*)alloc(NM * sizeof(double));
  float* inv_c = (float*)alloc((size_t)NB * NC * NC * sizeof(float));
  float* inv_s = (float*)alloc((size_t)NB * NC * NC * sizeof(float));
  float* sqr_s = (float*)alloc((size_t)NB * NC * NC * sizeof(float));
  float* ncwT = (float*)alloc((size_t)NB * NP * NC * sizeof(float));  // [p][c]
  float* nswT = (float*)alloc((size_t)NB * NP * NC * sizeof(float));  // [p][c]
  float* ssq = (float*)alloc((size_t)NB * NP * sizeof(float));
  float* rk = (float*)alloc((size_t)NB * NP * sizeof(float));
  unsigned long long* packed =
      (unsigned long long*)alloc((size_t)NB * NP * sizeof(unsigned long long));  // 128KB
  float* Dbuf = (float*)alloc((size_t)NP * NP * sizeof(float));  // 64MB, multi-overlaid:
  float* reass = Dbuf + (size_t)NB * NP * NC;          // [16MB, 32MB), used after score loop
  // raw fp16 split overlays Dbuf[0,32MB) — dead before dmat first writes Dbuf
  _Float16* Czh = (_Float16*)Dbuf;                       // 16MB: NM*NC*NP fp16
  _Float16* Czl = Czh + (size_t)NM * NC * NP;            // 16MB
  // whitened fp16 split arrays overlay pcov (dead after cov_reduce): 4 x 8MB
  _Float16* AhiT = (_Float16*)pcov;
  _Float16* AloT = AhiT + (size_t)NB * NP * NC;
  _Float16* BhiT = AloT + (size_t)NB * NP * NC;
  _Float16* BloT = BhiT + (size_t)NB * NP * NC;

  // 1-2: fused mean + raw split, then MFMA syrk cov
  meansplit_kernel<<<2 * NB * NC, 256, 0, stream>>>(content, style, mean, Czh, Czl);
  cov_mfma_kernel<<<dim3(10, KSPLIT, NM), 256, 0, stream>>>(Czh, Czl, pcov);
  cov_reduce_kernel<<<NM * NC * NC / 256, 256, 0, stream>>>(pcov, cov);

  // 3-4: Newton-Schulz inverse/forward sqrt in fp64 (Gershgorin-scaled,
  //      symmetric upper-tri tiles only)
  bound_init_kernel<<<NM, 256, 0, stream>>>(cov, Y0, Z0, scaleArr);
  double *Ya = Y0, *Za = Z0, *Yb = Y1, *Zb = Z1;
  for (int it = 0; it < NS_ITERS; it++) {
    ns_t_kernel<<<dim3(NTILE8, 1, NM), 256, 0, stream>>>(Za, Ya, T);
    ns_upd_kernel<<<dim3(NTILE8, 1, NM * 2), 256, 0, stream>>>(Ya, Za, T, Yb, Zb);
    double* tmp;
    tmp = Ya; Ya = Yb; Yb = tmp;
    tmp = Za; Za = Zb; Zb = tmp;
  }
  finalize_kernel<<<dim3(NB * NC * NC / 256, 3), 256, 0, stream>>>(Ya, Za, scaleArr,
                                                                   inv_c, inv_s, sqr_s);

  // 6: whiten both features, output [p][c] directly
  whiten_kernel<<<dim3(NP / 128, NC / 64, 2 * NB), 256, 0, stream>>>(
      content, style, mean, inv_c, inv_s, ncwT, nswT);

  // 7: fused fp16 split + style ssq (row-wise), then knorm box
  split_kernel<<<dim3(NP / 4, 1, 2 * NB), 256, 0, stream>>>(ncwT, nswT,
                                                            BhiT, BloT, AhiT, AloT, ssq);
  rknorm_kernel<<<NB * NP / 256, 256, 0, stream>>>(ssq, rk);

  // 8-9: zero packed argmax keys (re-poisoned each call), then per batch:
  //      D = A B^T (MFMA fp16 3-term), score with fused atomicMax argmax
  hipMemsetAsync(packed, 0, (size_t)NB * NP * sizeof(unsigned long long), stream);
  for (int b = 0; b < NB; b++) {
    dmat_kernel<<<dim3(NP / 128, NP / 128), 256, 0, stream>>>(AhiT, AloT, BhiT, BloT, Dbuf, b);
    score_kernel<<<dim3(NP / 256, NSLAB), 256, 0, stream>>>(Dbuf, rk, packed, b);
  }

  // 11: reassembly (gather form) straight from nswT, unpacking argmax keys
  reassemble_kernel<<<NB * NP, 256, 0, stream>>>(nswT, packed, reass);

  // 12: coloring straight into d_out (style_strength == 1.0)
  coloring_kernel<<<dim3(NC / 64, NP / 64, NB), 256, 0, stream>>>(sqr_s, reass, mean, out);
}

// Round 16
// 956.526 us; speedup vs baseline: 1.3730x; 1.1357x over previous
//
#include <hip/hip_runtime.h>
#include <stdint.h>

// Problem constants
constexpr int NB = 4;      // batch
constexpr int NC = 256;    // channels
constexpr int HW = 64;     // spatial side
constexpr int NP = 4096;   // HW*HW
constexpr int NM = 8;      // matrices for Newton-Schulz: 2 feats x 4 batches
constexpr int NS_ITERS = 7;       // lam_scaled ~0.135 -> residual saturates fp32 eps at 7
constexpr int NSLAB = 128;        // score slabs (combine fused via atomicMax)
constexpr int PSLAB = NP / NSLAB; // 32
constexpr int KSPLIT = 8;         // cov K-split
constexpr int KCHUNK = NP / KSPLIT; // 512
constexpr int NTILE8 = 36;        // upper-tri 32-tiles in 8x8 grid (NS symmetric)

// fp16 Markidis split (bf16 2-split caused argmax flips). Pre-scale by 512
// keeps lo out of fp16-subnormal range; uniform scaling is argmax-invariant
// for D, and is divided back out for cov.
constexpr float SPLIT_SCALE = 512.0f;
constexpr double COV_DESCALE = 1.0 / ((double)SPLIT_SCALE * (double)SPLIT_SCALE);

typedef __attribute__((ext_vector_type(8))) _Float16 h8v;  // 8 fp16 (4 VGPRs)
typedef __attribute__((ext_vector_type(4))) _Float16 h4v;  // 4 fp16 (8B store)
typedef __attribute__((ext_vector_type(4))) float f4v;     // MFMA acc

// async global->LDS, 16B per lane; lds arg must be wave-uniform
#define GLD16(lds, g)                                                        \
  __builtin_amdgcn_global_load_lds(                                          \
      (const __attribute__((address_space(1))) void*)(g),                    \
      (__attribute__((address_space(3))) void*)(lds), 16, 0, 0)

// monotone float -> sortable u32 (finite inputs): order(f) == order(sortable(f))
__device__ inline unsigned sortable_f32(float f) {
  unsigned u = __float_as_uint(f);
  return (u & 0x80000000u) ? ~u : (u | 0x80000000u);
}

// ---------------------------------------------------------------------------
// 1. fused mean + raw fp16 split: (src-mu)*512 -> fp16 hi/lo in [c][p]
__global__ __launch_bounds__(256) void meansplit_kernel(const float* __restrict__ content,
                                                        const float* __restrict__ style,
                                                        float* __restrict__ mean,
                                                        _Float16* __restrict__ Czh,
                                                        _Float16* __restrict__ Czl) {
  int id = blockIdx.x;              // [0, 2*NB*NC) == m*NC + c
  int feat = id / (NB * NC);
  int bc = id % (NB * NC);
  const float* src = (feat ? style : content) + (size_t)bc * NP;
  int tid = threadIdx.x;
  float s = 0.f;
  for (int i = tid; i < NP; i += 256) s += src[i];
  __shared__ float red[256];
  red[tid] = s;
  __syncthreads();
  for (int st = 128; st > 0; st >>= 1) {
    if (tid < st) red[tid] += red[tid + st];
    __syncthreads();
  }
  float mu = red[0] * (1.0f / NP);
  if (tid == 0) mean[id] = mu;
  _Float16* oh = Czh + (size_t)id * NP;
  _Float16* ol = Czl + (size_t)id * NP;
  for (int f4 = tid; f4 < NP / 4; f4 += 256) {
    float4 v = *(const float4*)&src[f4 * 4];
    float vv[4] = {v.x, v.y, v.z, v.w};
    h4v h, l;
#pragma unroll
    for (int q = 0; q < 4; q++) {
      float sv = (vv[q] - mu) * SPLIT_SCALE;
      _Float16 hh = (_Float16)sv;
      h[q] = hh;
      l[q] = (_Float16)(sv - (float)hh);
    }
    *(h4v*)&oh[f4 * 4] = h;
    *(h4v*)&ol[f4 * 4] = l;
  }
}

// ---------------------------------------------------------------------------
// 2. MFMA syrk cov: 64x64 upper-tri tiles, 4-term fp16 split, per-32-k fp64 fold
__global__ __launch_bounds__(256) void cov_mfma_kernel(const _Float16* __restrict__ Czh,
                                                       const _Float16* __restrict__ Czl,
                                                       double* __restrict__ pcov) {
  __shared__ _Float16 sAh[64 * 32], sAl[64 * 32], sBh[64 * 32], sBl[64 * 32];
  int m = blockIdx.z;
  int t = blockIdx.x, ti = 0, rem = t;
  while (rem >= 4 - ti) { rem -= 4 - ti; ti++; }
  int tj = ti + rem;
  int i0 = ti * 64, j0 = tj * 64;
  const _Float16* Ah = Czh + ((size_t)m * NC + i0) * NP;
  const _Float16* Al = Czl + ((size_t)m * NC + i0) * NP;
  const _Float16* Bh = Czh + ((size_t)m * NC + j0) * NP;
  const _Float16* Bl = Czl + ((size_t)m * NC + j0) * NP;
  int k0base = blockIdx.y * KCHUNK;
  int tid = threadIdx.x, lane = tid & 63;
  int mm = lane & 15, quad = lane >> 4;
  int w = tid >> 6, qr = w & 1, qc = w >> 1;
  double dacc[2][2][4] = {};
  for (int step = 0; step < KCHUNK / 32; step++) {
    int k0 = k0base + step * 32;
    __syncthreads();
    {
      int row = tid >> 2, koff = (tid & 3) * 8;
      int sbase = (tid & ~63) * 8;   // wave-uniform
      GLD16(&sAh[sbase], Ah + (size_t)row * NP + k0 + koff);
      GLD16(&sAl[sbase], Al + (size_t)row * NP + k0 + koff);
      GLD16(&sBh[sbase], Bh + (size_t)row * NP + k0 + koff);
      GLD16(&sBl[sbase], Bl + (size_t)row * NP + k0 + koff);
    }
    __syncthreads();   // drains vmcnt per barrier semantics
    h8v afh[2], afl[2], bfh[2], bfl[2];
#pragma unroll
    for (int tt = 0; tt < 2; tt++) {
      int ra = (qr * 32 + tt * 16 + mm) * 32 + quad * 8;
      afh[tt] = *(const h8v*)&sAh[ra];
      afl[tt] = *(const h8v*)&sAl[ra];
      int rb = (qc * 32 + tt * 16 + mm) * 32 + quad * 8;
      bfh[tt] = *(const h8v*)&sBh[rb];
      bfl[tt] = *(const h8v*)&sBl[rb];
    }
    f4v acc[2][2] = {};
#pragma unroll
    for (int tr = 0; tr < 2; tr++)
#pragma unroll
      for (int tc = 0; tc < 2; tc++) {
        acc[tr][tc] = __builtin_amdgcn_mfma_f32_16x16x32_f16(afh[tr], bfh[tc], acc[tr][tc], 0, 0, 0);
        acc[tr][tc] = __builtin_amdgcn_mfma_f32_16x16x32_f16(afh[tr], bfl[tc], acc[tr][tc], 0, 0, 0);
        acc[tr][tc] = __builtin_amdgcn_mfma_f32_16x16x32_f16(afl[tr], bfh[tc], acc[tr][tc], 0, 0, 0);
        acc[tr][tc] = __builtin_amdgcn_mfma_f32_16x16x32_f16(afl[tr], bfl[tc], acc[tr][tc], 0, 0, 0);
      }
#pragma unroll
    for (int tr = 0; tr < 2; tr++)
#pragma unroll
      for (int tc = 0; tc < 2; tc++)
#pragma unroll
        for (int r = 0; r < 4; r++) dacc[tr][tc][r] += (double)acc[tr][tc][r];
  }
  double* dst = pcov + ((size_t)blockIdx.y * NM + m) * NC * NC;
  // C/D layout: col = lane&15, row = quad*4 + reg  [verified mapping]
#pragma unroll
  for (int tr = 0; tr < 2; tr++)
#pragma unroll
    for (int tc = 0; tc < 2; tc++)
#pragma unroll
      for (int r = 0; r < 4; r++) {
        int row = i0 + qr * 32 + tr * 16 + quad * 4 + r;
        int col = j0 + qc * 32 + tc * 16 + mm;
        dst[(size_t)row * NC + col] = dacc[tr][tc][r];
      }
}

// 2b. sum K-split partials; mirror lower triangle from upper tiles; descale
__global__ __launch_bounds__(256) void cov_reduce_kernel(const double* __restrict__ pcov,
                                                         double* __restrict__ cov) {
  size_t idx = (size_t)blockIdx.x * 256 + threadIdx.x;  // [0, NM*NC*NC)
  int m = (int)(idx >> 16);
  int ij = (int)(idx & 65535);
  int i = ij >> 8, j = ij & 255;
  int src = ((i >> 6) <= (j >> 6)) ? ij : ((j << 8) | i);
  double s = 0;
  for (int k = 0; k < KSPLIT; k++)
    s += pcov[((size_t)k * NM + m) * 65536 + src];
  cov[idx] = s * COV_DESCALE;
}

// ---------------------------------------------------------------------------
// 3. Gershgorin bound; init Y = s*A, Z = I. R16: Y/Z now fp32 (coupled NS is
//    stable, err ~ cond*eps_f32 ~ 2e-7 rel — below the accepted fp16-split
//    perturbation). scaleArr stays fp64.
__global__ __launch_bounds__(256) void bound_init_kernel(const double* __restrict__ cov,
                                                         float* __restrict__ Y,
                                                         float* __restrict__ Z,
                                                         double* __restrict__ scaleArr) {
  int m = blockIdx.x;
  const double* A = cov + (size_t)m * NC * NC;
  int t = threadIdx.x;
  double s = 0;
  for (int i = 0; i < NC; i++) s += fabs(A[(size_t)i * NC + t]);   // coalesced
  __shared__ double red[256];
  red[t] = s;
  __syncthreads();
  for (int st = 128; st > 0; st >>= 1) {
    if (t < st) red[t] = fmax(red[t], red[t + st]);
    __syncthreads();
  }
  double scale = 1.0 / red[0];     // lam_max <= max abs row sum (rigorous upper bound)
  if (t == 0) scaleArr[m] = scale;
  float* Ym = Y + (size_t)m * NC * NC;
  float* Zm = Z + (size_t)m * NC * NC;
  for (int idx = t; idx < NC * NC; idx += 256) {
    Ym[idx] = (float)(A[idx] * scale);
    Zm[idx] = ((idx / NC) == (idx % NC)) ? 1.0f : 0.0f;
  }
}

// ---------------------------------------------------------------------------
// NS iterates are polynomials in symmetric A -> Y, Z, T, Y*T, T*Z all
// symmetric. Upper-tri 32x32 tiles only, mirror-write lower. R16: fp32.

// 4a. T = Z * Y (fp32, upper-tri 32x32 tiles, 2x2 micro, mirrored writes)
__global__ __launch_bounds__(256) void ns_t_kernel(const float* __restrict__ Zin,
                                                   const float* __restrict__ Yin,
                                                   float* __restrict__ T) {
  int m = blockIdx.z;
  const float* Am = Zin + (size_t)m * NC * NC;
  const float* Bm = Yin + (size_t)m * NC * NC;
  float* Tm = T + (size_t)m * NC * NC;
  __shared__ float As[32][33];
  __shared__ float Bs[32][33];
  int tid = threadIdx.x, tx = tid & 15, ty = tid >> 4;
  int t = blockIdx.x, ti = 0, rem = t;     // unrank upper-tri tile (8x8 grid)
  while (rem >= 8 - ti) { rem -= 8 - ti; ti++; }
  int tj = ti + rem;
  int i0 = ti * 32, j0 = tj * 32;
  float a00 = 0, a01 = 0, a10 = 0, a11 = 0;
  for (int k0 = 0; k0 < NC; k0 += 32) {
    for (int idx = tid; idx < 1024; idx += 256) {
      int r = idx >> 5, cc = idx & 31;
      As[r][cc] = Am[(size_t)(i0 + r) * NC + k0 + cc];
      Bs[r][cc] = Bm[(size_t)(k0 + r) * NC + j0 + cc];
    }
    __syncthreads();
#pragma unroll
    for (int kk = 0; kk < 32; kk++) {
      float x0 = As[ty * 2][kk], x1 = As[ty * 2 + 1][kk];
      float y0 = Bs[kk][tx * 2], y1 = Bs[kk][tx * 2 + 1];
      a00 += x0 * y0; a01 += x0 * y1; a10 += x1 * y0; a11 += x1 * y1;
    }
    __syncthreads();
  }
  Tm[(size_t)(i0 + ty * 2) * NC + j0 + tx * 2] = a00;
  Tm[(size_t)(i0 + ty * 2) * NC + j0 + tx * 2 + 1] = a01;
  Tm[(size_t)(i0 + ty * 2 + 1) * NC + j0 + tx * 2] = a10;
  Tm[(size_t)(i0 + ty * 2 + 1) * NC + j0 + tx * 2 + 1] = a11;
  if (ti != tj) {   // mirror tile, coalesced via LDS transpose (reuse As)
    As[ty * 2][tx * 2] = a00;
    As[ty * 2][tx * 2 + 1] = a01;
    As[ty * 2 + 1][tx * 2] = a10;
    As[ty * 2 + 1][tx * 2 + 1] = a11;
    __syncthreads();
    for (int idx = tid; idx < 1024; idx += 256) {
      int r = idx >> 5, cc = idx & 31;
      Tm[(size_t)(j0 + r) * NC + i0 + cc] = As[cc][r];
    }
  }
}

// 4b. Yout = 1.5*Yin - 0.5*Yin*T ; Zout = 1.5*Zin - 0.5*T*Zin  (fp32)
__global__ __launch_bounds__(256) void ns_upd_kernel(const float* __restrict__ Yin,
                                                     const float* __restrict__ Zin,
                                                     const float* __restrict__ T,
                                                     float* __restrict__ Yout,
                                                     float* __restrict__ Zout) {
  int z = blockIdx.z;
  int m = z & 7, which = z >> 3;
  size_t off = (size_t)m * NC * NC;
  const float* Am = which == 0 ? (Yin + off) : (T + off);
  const float* Bm = which == 0 ? (T + off) : (Zin + off);
  const float* Sm = which == 0 ? (Yin + off) : (Zin + off);
  float* Om = which == 0 ? (Yout + off) : (Zout + off);
  __shared__ float As[32][33];
  __shared__ float Bs[32][33];
  int tid = threadIdx.x, tx = tid & 15, ty = tid >> 4;
  int t = blockIdx.x, ti = 0, rem = t;     // unrank upper-tri tile (8x8 grid)
  while (rem >= 8 - ti) { rem -= 8 - ti; ti++; }
  int tj = ti + rem;
  int i0 = ti * 32, j0 = tj * 32;
  float a00 = 0, a01 = 0, a10 = 0, a11 = 0;
  for (int k0 = 0; k0 < NC; k0 += 32) {
    for (int idx = tid; idx < 1024; idx += 256) {
      int r = idx >> 5, cc = idx & 31;
      As[r][cc] = Am[(size_t)(i0 + r) * NC + k0 + cc];
      Bs[r][cc] = Bm[(size_t)(k0 + r) * NC + j0 + cc];
    }
    __syncthreads();
#pragma unroll
    for (int kk = 0; kk < 32; kk++) {
      float x0 = As[ty * 2][kk], x1 = As[ty * 2 + 1][kk];
      float y0 = Bs[kk][tx * 2], y1 = Bs[kk][tx * 2 + 1];
      a00 += x0 * y0; a01 += x0 * y1; a10 += x1 * y0; a11 += x1 * y1;
    }
    __syncthreads();
  }
  int r0 = i0 + ty * 2, c0 = j0 + tx * 2;
  float o00 = 1.5f * Sm[(size_t)r0 * NC + c0] - 0.5f * a00;
  float o01 = 1.5f * Sm[(size_t)r0 * NC + c0 + 1] - 0.5f * a01;
  float o10 = 1.5f * Sm[(size_t)(r0 + 1) * NC + c0] - 0.5f * a10;
  float o11 = 1.5f * Sm[(size_t)(r0 + 1) * NC + c0 + 1] - 0.5f * a11;
  Om[(size_t)r0 * NC + c0] = o00;
  Om[(size_t)r0 * NC + c0 + 1] = o01;
  Om[(size_t)(r0 + 1) * NC + c0] = o10;
  Om[(size_t)(r0 + 1) * NC + c0 + 1] = o11;
  if (ti != tj) {   // mirror tile via LDS transpose (reuse As)
    As[ty * 2][tx * 2] = o00;
    As[ty * 2][tx * 2 + 1] = o01;
    As[ty * 2 + 1][tx * 2] = o10;
    As[ty * 2 + 1][tx * 2 + 1] = o11;
    __syncthreads();
    for (int idx = tid; idx < 1024; idx += 256) {
      int r = idx >> 5, cc = idx & 31;
      Om[(size_t)(j0 + r) * NC + i0 + cc] = As[cc][r];
    }
  }
}

// ---------------------------------------------------------------------------
// 5. finalize: inv_c = Z_c*sqrt(s), inv_s = Z_s*sqrt(s), sqr_s = Y_s/sqrt(s)
//    R16: Yf/Zf now fp32; scale math in fp64.
__global__ __launch_bounds__(256) void finalize_kernel(const float* __restrict__ Yf,
                                                       const float* __restrict__ Zf,
                                                       const double* __restrict__ scaleArr,
                                                       float* __restrict__ inv_c,
                                                       float* __restrict__ inv_s,
                                                       float* __restrict__ sqr_s) {
  int which = blockIdx.y;
  int idx = blockIdx.x * 256 + threadIdx.x;   // [0, NB*NC*NC)
  int b = idx >> 16;
  int ij = idx & 65535;
  if (which == 0) {
    double s = sqrt(scaleArr[b]);
    inv_c[idx] = (float)((double)Zf[(size_t)b * 65536 + ij] * s);
  } else if (which == 1) {
    double s = sqrt(scaleArr[4 + b]);
    inv_s[idx] = (float)((double)Zf[(size_t)(4 + b) * 65536 + ij] * s);
  } else {
    double s = sqrt(scaleArr[4 + b]);
    sqr_s[idx] = (float)((double)Yf[(size_t)(4 + b) * 65536 + ij] / s);
  }
}

// ---------------------------------------------------------------------------
// 6. whitening: outT[x][c] = sum_k (src[k][x]-mu[k]) * M[k][c]. Emits [p][c]
//    directly. M symmetric -> Ms[k][c] staged from M rows (float4, conflict-free).
//    128x64 tile, 8x4 micro.
__global__ __launch_bounds__(256) void whiten_kernel(const float* __restrict__ content,
                                                     const float* __restrict__ style,
                                                     const float* __restrict__ mean,
                                                     const float* __restrict__ inv_c,
                                                     const float* __restrict__ inv_s,
                                                     float* __restrict__ ncwT,
                                                     float* __restrict__ nswT) {
  int z = blockIdx.z; int feat = z >> 2, b = z & 3;
  const float* src = (feat ? style : content) + (size_t)b * NC * NP;
  const float* mu = mean + (size_t)feat * NB * NC + b * NC;
  const float* M = (feat ? inv_s : inv_c) + (size_t)b * NC * NC;
  float* dst = (feat ? nswT : ncwT) + (size_t)b * NP * NC;   // [p][c]
  int x0 = blockIdx.x * 128, c0 = blockIdx.y * 64;
  __shared__ float Ms[32][68];    // [k][c]
  __shared__ float Xs[32][136];   // [k][x]
  int tid = threadIdx.x, tx = tid & 15, ty = tid >> 4;
  float acc[8][4] = {};   // [x_i][c_j]
  for (int k0 = 0; k0 < NC; k0 += 32) {
    for (int idx = tid; idx < 512; idx += 256) {
      int kk = idx >> 4, r4 = (idx & 15) * 4;
      *(float4*)&Ms[kk][r4] = *(const float4*)&M[(size_t)(k0 + kk) * NC + c0 + r4];
    }
    for (int idx = tid; idx < 1024; idx += 256) {
      int r = idx >> 5, c4 = (idx & 31) * 4;
      float4 v = *(const float4*)&src[(size_t)(k0 + r) * NP + x0 + c4];
      float mm = mu[k0 + r];
      v.x -= mm; v.y -= mm; v.z -= mm; v.w -= mm;
      *(float4*)&Xs[r][c4] = v;
    }
    __syncthreads();
#pragma unroll
    for (int kk = 0; kk < 32; kk++) {
      float4 xa = *(const float4*)&Xs[kk][ty * 8];
      float4 xb = *(const float4*)&Xs[kk][ty * 8 + 4];
      float4 mv = *(const float4*)&Ms[kk][tx * 4];
      float xv[8] = {xa.x, xa.y, xa.z, xa.w, xb.x, xb.y, xb.z, xb.w};
      float mm4[4] = {mv.x, mv.y, mv.z, mv.w};
#pragma unroll
      for (int i = 0; i < 8; i++)
#pragma unroll
        for (int j = 0; j < 4; j++) acc[i][j] += xv[i] * mm4[j];
    }
    __syncthreads();
  }
#pragma unroll
  for (int i = 0; i < 8; i++)
    *(float4*)&dst[(size_t)(x0 + ty * 8 + i) * NC + c0 + tx * 4] =
        make_float4(acc[i][0], acc[i][1], acc[i][2], acc[i][3]);
}

// ---------------------------------------------------------------------------
// 7. fused row-wise fp16 Markidis split + style ssq (one wave per row y)
__global__ __launch_bounds__(256) void split_kernel(const float* __restrict__ ncwT,
                                                    const float* __restrict__ nswT,
                                                    _Float16* __restrict__ BhiT,
                                                    _Float16* __restrict__ BloT,
                                                    _Float16* __restrict__ AhiT,
                                                    _Float16* __restrict__ AloT,
                                                    float* __restrict__ ssq) {
  int z = blockIdx.z; int feat = z >> 2, b = z & 3;
  int wave = threadIdx.x >> 6, lane = threadIdx.x & 63;
  int y = blockIdx.x * 4 + wave;
  const float* src = (feat ? nswT : ncwT) + ((size_t)b * NP + y) * NC;
  _Float16* oh = (feat ? AhiT : BhiT) + ((size_t)b * NP + y) * NC;
  _Float16* ol = (feat ? AloT : BloT) + ((size_t)b * NP + y) * NC;
  float4 v = *(const float4*)&src[lane * 4];
  float vv[4] = {v.x, v.y, v.z, v.w};
  h4v h, l;
#pragma unroll
  for (int q = 0; q < 4; q++) {
    float sv = vv[q] * SPLIT_SCALE;
    _Float16 hh = (_Float16)sv;          // v_cvt_f16_f32, RTN
    h[q] = hh;
    l[q] = (_Float16)(sv - (float)hh);
  }
  *(h4v*)&oh[lane * 4] = h;
  *(h4v*)&ol[lane * 4] = l;
  if (feat) {
    float s = vv[0] * vv[0] + vv[1] * vv[1] + vv[2] * vv[2] + vv[3] * vv[3];
#pragma unroll
    for (int off = 32; off > 0; off >>= 1) s += __shfl_down(s, off);
    if (lane == 0) ssq[b * NP + y] = s;
  }
}

__global__ __launch_bounds__(256) void rknorm_kernel(const float* __restrict__ ssq,
                                                     float* __restrict__ rk) {
  int idx = blockIdx.x * 256 + threadIdx.x;
  int b = idx >> 12, p = idx & 4095;
  int pi = p >> 6, pj = p & 63;
  float s = 0.f;
#pragma unroll
  for (int d = -1; d <= 1; d++)
#pragma unroll
    for (int e = -1; e <= 1; e++) {
      if ((unsigned)(pi + d) < 64u && (unsigned)(pj + e) < 64u)
        s += ssq[b * NP + (pi + d) * 64 + pj + e];
    }
  rk[idx] = 1.0f / sqrtf(s);
}

// ---------------------------------------------------------------------------
// 8. MFMA: D[p][x] = sum_c A[p][c]*B[x][c] via 3-term fp16 split (hh, hl, lh).
//    128x128 tile/block, 4 waves each 64x64 (4x4 of mfma_f32_16x16x32_f16),
//    BK=32, global_load_lds 16B staging.
__global__ __launch_bounds__(256) void dmat_kernel(const _Float16* __restrict__ AhiT,
                                                   const _Float16* __restrict__ AloT,
                                                   const _Float16* __restrict__ BhiT,
                                                   const _Float16* __restrict__ BloT,
                                                   float* __restrict__ D, int b) {
  __shared__ _Float16 sAh[128 * 32], sAl[128 * 32], sBh[128 * 32], sBl[128 * 32];
  const _Float16* Ah = AhiT + (size_t)b * NP * NC;
  const _Float16* Al = AloT + (size_t)b * NP * NC;
  const _Float16* Bh = BhiT + (size_t)b * NP * NC;
  const _Float16* Bl = BloT + (size_t)b * NP * NC;
  int p0 = blockIdx.x * 128, x0 = blockIdx.y * 128;
  int tid = threadIdx.x, lane = tid & 63;
  int m = lane & 15, quad = lane >> 4;
  int w = tid >> 6, qr = w & 1, qc = w >> 1;
  f4v acc[4][4] = {};
  for (int step = 0; step < NC / 32; step++) {
    int c0 = step * 32;
    __syncthreads();
#pragma unroll
    for (int i = 0; i < 2; i++) {
      int seg = i * 256 + tid;
      int row = seg >> 2, koff = (seg & 3) * 8;
      int sbase = (i * 256 + (tid & ~63)) * 8;   // wave-uniform
      GLD16(&sAh[sbase], Ah + (size_t)(p0 + row) * NC + c0 + koff);
      GLD16(&sAl[sbase], Al + (size_t)(p0 + row) * NC + c0 + koff);
      GLD16(&sBh[sbase], Bh + (size_t)(x0 + row) * NC + c0 + koff);
      GLD16(&sBl[sbase], Bl + (size_t)(x0 + row) * NC + c0 + koff);
    }
    __syncthreads();   // drains vmcnt (global_load_lds) per barrier semantics
    h8v afh[4], afl[4], bfh[4], bfl[4];
#pragma unroll
    for (int t = 0; t < 4; t++) {
      int ra = (qr * 64 + t * 16 + m) * 32 + quad * 8;
      afh[t] = *(const h8v*)&sAh[ra];
      afl[t] = *(const h8v*)&sAl[ra];
      int rb = (qc * 64 + t * 16 + m) * 32 + quad * 8;
      bfh[t] = *(const h8v*)&sBh[rb];
      bfl[t] = *(const h8v*)&sBl[rb];
    }
#pragma unroll
    for (int tr = 0; tr < 4; tr++)
#pragma unroll
      for (int tc = 0; tc < 4; tc++) {
        acc[tr][tc] = __builtin_amdgcn_mfma_f32_16x16x32_f16(afh[tr], bfh[tc], acc[tr][tc], 0, 0, 0);
        acc[tr][tc] = __builtin_amdgcn_mfma_f32_16x16x32_f16(afh[tr], bfl[tc], acc[tr][tc], 0, 0, 0);
        acc[tr][tc] = __builtin_amdgcn_mfma_f32_16x16x32_f16(afl[tr], bfh[tc], acc[tr][tc], 0, 0, 0);
      }
  }
  // C/D layout: col = lane&15, row = quad*4 + reg  [verified mapping]
#pragma unroll
  for (int tr = 0; tr < 4; tr++)
#pragma unroll
    for (int tc = 0; tc < 4; tc++)
#pragma unroll
      for (int r = 0; r < 4; r++) {
        int row = p0 + qr * 64 + tr * 16 + quad * 4 + r;
        int col = x0 + qc * 64 + tc * 16 + m;
        D[(size_t)row * NP + col] = acc[tr][tc][r];
      }
}

// ---------------------------------------------------------------------------
// 9. score: shifted-sum + slab-local argmax, cross-slab reduction via packed
//    u64 atomicMax: key = (sortable(score)<<32) | ~p (first-max tie rule).
__global__ __launch_bounds__(256) void score_kernel(const float* __restrict__ D,
                                                    const float* __restrict__ rk,
                                                    unsigned long long* __restrict__ packed,
                                                    int b) {
  int x = blockIdx.x * 256 + threadIdx.x;
  int slab = blockIdx.y;
  int xi = x >> 6, xj = x & 63;
  const float* rkb = rk + (size_t)b * NP;
  bool xm[9];
#pragma unroll
  for (int q = 0; q < 9; q++) {
    int d = q / 3 - 1, e = q % 3 - 1;
    xm[q] = ((unsigned)(xi + d) < 64u) && ((unsigned)(xj + e) < 64u);
  }
  float best = -1e30f;
  int bi = 0;
  int p0 = slab * PSLAB;
  for (int p = p0; p < p0 + PSLAB; p++) {
    int pi = p >> 6, pj = p & 63;
    float acc = 0.f;
#pragma unroll
    for (int q = 0; q < 9; q++) {
      int d = q / 3 - 1, e = q % 3 - 1;
      int off = d * 64 + e;
      bool ok = xm[q] && ((unsigned)(pi + d) < 64u) && ((unsigned)(pj + e) < 64u);
      int row = ok ? p + off : p;
      int col = ok ? x + off : x;
      float t = D[(size_t)row * NP + col];
      acc += ok ? t : 0.f;
    }
    float s = acc * rkb[p];
    if (s > best) { best = s; bi = p; }
  }
  unsigned long long key = ((unsigned long long)sortable_f32(best) << 32) |
                           (unsigned)(~(unsigned)bi);
  atomicMax(&packed[(size_t)b * NP + x], key);
}

// ---------------------------------------------------------------------------
// 11. gather-form overlap-add reassembly, divided by deconv norm (reads nswT [p][c]).
//     Unpacks argmax p from the packed u64 (p = ~lo & 4095).
__global__ __launch_bounds__(256) void reassemble_kernel(const float* __restrict__ nswT,
                                                         const unsigned long long* __restrict__ packed,
                                                         float* __restrict__ reass) {
  int by = blockIdx.x;       // b*NP + y
  int b = by >> 12, y = by & 4095;
  int yi = y >> 6, yj = y & 63;
  int t = threadIdx.x;       // channel
  float acc = 0.f;
#pragma unroll
  for (int oi = 0; oi < 3; oi++)
#pragma unroll
    for (int oj = 0; oj < 3; oj++) {
      int xi = yi + 1 - oi, xj = yj + 1 - oj;
      if ((unsigned)xi < 64u && (unsigned)xj < 64u) {
        unsigned long long v = packed[(size_t)b * NP + xi * 64 + xj];
        int p = (int)((~(unsigned)(v & 0xFFFFFFFFull)) & 4095u);
        int qi = (p >> 6) + oi - 1, qj = (p & 63) + oj - 1;
        if ((unsigned)qi < 64u && (unsigned)qj < 64u)
          acc += nswT[((size_t)b * NP + qi * 64 + qj) * NC + t];
      }
    }
  int cy = (yi == 0 || yi == 63) ? 2 : 3;
  int cx = (yj == 0 || yj == 63) ? 2 : 3;
  reass[((size_t)b * NP + y) * NC + t] = acc / (float)(cy * cx);
}

// ---------------------------------------------------------------------------
// 12. coloring: out[b][c][y] = sum_j sqr_s[b][c][j]*reass[b][y][j] + mean_s[b][c].
//     sqr_s symmetric -> As staged from rows (float4, conflict-free).
__global__ __launch_bounds__(256) void coloring_kernel(const float* __restrict__ sqr_s,
                                                       const float* __restrict__ reass,
                                                       const float* __restrict__ mean,
                                                       float* __restrict__ out) {
  int b = blockIdx.z;
  const float* A = sqr_s + (size_t)b * NC * NC;
  const float* Bm = reass + (size_t)b * NP * NC;
  const float* mu = mean + (size_t)NB * NC + b * NC;
  float* dst = out + (size_t)b * NC * NP;
  int c0 = blockIdx.x * 64, y0 = blockIdx.y * 64;
  __shared__ float As[32][68];   // [j][c], float4 rows
  __shared__ float Bs[32][66];   // [j][y], transposed scalar writes
  int tid = threadIdx.x, tx = tid & 15, ty = tid >> 4;
  float acc[4][4] = {};
  for (int k0 = 0; k0 < NC; k0 += 32) {
    for (int idx = tid; idx < 512; idx += 256) {
      int kk = idx >> 4, r4 = (idx & 15) * 4;   // A symmetric: row k, cols c
      *(float4*)&As[kk][r4] = *(const float4*)&A[(size_t)(k0 + kk) * NC + c0 + r4];
    }
    for (int idx = tid; idx < 2048; idx += 256) {
      int r = idx >> 5, kk = idx & 31;
      Bs[kk][r] = Bm[(size_t)(y0 + r) * NC + k0 + kk];
    }
    __syncthreads();
#pragma unroll
    for (int kk = 0; kk < 32; kk++) {
      float4 av = *(const float4*)&As[kk][ty * 4];
      float a[4] = {av.x, av.y, av.z, av.w};
      float bb[4];
      *(float2*)&bb[0] = *(const float2*)&Bs[kk][tx * 4];
      *(float2*)&bb[2] = *(const float2*)&Bs[kk][tx * 4 + 2];
#pragma unroll
      for (int i = 0; i < 4; i++)
#pragma unroll
        for (int j = 0; j < 4; j++) acc[i][j] += a[i] * bb[j];
    }
    __syncthreads();
  }
#pragma unroll
  for (int i = 0; i < 4; i++) {
    float m = mu[c0 + ty * 4 + i];
    float4 v = make_float4(acc[i][0] + m, acc[i][1] + m, acc[i][2] + m, acc[i][3] + m);
    *(float4*)&dst[(size_t)(c0 + ty * 4 + i) * NP + y0 + tx * 4] = v;
  }
}

// ---------------------------------------------------------------------------
extern "C" void kernel_launch(void* const* d_in, const int* in_sizes, int n_in,
                              void* d_out, int out_size, void* d_ws, size_t ws_size,
                              hipStream_t stream) {
  (void)in_sizes; (void)n_in; (void)out_size; (void)ws_size;
  const float* content = (const float*)d_in[0];
  const float* style = (const float*)d_in[1];
  float* out = (float*)d_out;

  // workspace carve-up (256B aligned)
  char* w = (char*)d_ws;
  auto alloc = [&](size_t bytes) -> void* {
    void* p = (void*)w;
    w += (bytes + 255) & ~(size_t)255;
    return p;
  };
  float* mean = (float*)alloc(2 * NB * NC * sizeof(float));
  double* pcov = (double*)alloc((size_t)KSPLIT * NM * NC * NC * sizeof(double));  // 32MB
  double* cov = (double*)alloc((size_t)NM * NC * NC * sizeof(double));
  float* Y0 = (float*)alloc((size_t)NM * NC * NC * sizeof(float));   // R16: fp32 NS state
  float* Z0 = (float*)alloc((size_t)NM * NC * NC * sizeof(float));
  float* Y1 = (float*)alloc((size_t)NM * NC * NC * sizeof(float));
  float* Z1 = (float*)alloc((size_t)NM * NC * NC * sizeof(float));
  float* T = (float*)alloc((size_t)NM * NC * NC * sizeof(float));
  double* scaleArr = (double*)alloc(NM * sizeof(double));
  float* inv_c = (float*)alloc((size_t)NB * NC * NC * sizeof(float));
  float* inv_s = (float*)alloc((size_t)NB * NC * NC * sizeof(float));
  float* sqr_s = (float*)alloc((size_t)NB * NC * NC * sizeof(float));
  float* ncwT = (float*)alloc((size_t)NB * NP * NC * sizeof(float));  // [p][c]
  float* nswT = (float*)alloc((size_t)NB * NP * NC * sizeof(float));  // [p][c]
  float* ssq = (float*)alloc((size_t)NB * NP * sizeof(float));
  float* rk = (float*)alloc((size_t)NB * NP * sizeof(float));
  unsigned long long* packed =
      (unsigned long long*)alloc((size_t)NB * NP * sizeof(unsigned long long));  // 128KB
  float* Dbuf = (float*)alloc((size_t)NP * NP * sizeof(float));  // 64MB, multi-overlaid:
  float* reass = Dbuf + (size_t)NB * NP * NC;          // [16MB, 32MB), used after score loop
  // raw fp16 split overlays Dbuf[0,32MB) — dead before dmat first writes Dbuf
  _Float16* Czh = (_Float16*)Dbuf;                       // 16MB: NM*NC*NP fp16
  _Float16* Czl = Czh + (size_t)NM * NC * NP;            // 16MB
  // whitened fp16 split arrays overlay pcov (dead after cov_reduce): 4 x 8MB
  _Float16* AhiT = (_Float16*)pcov;
  _Float16* AloT = AhiT + (size_t)NB * NP * NC;
  _Float16* BhiT = AloT + (size_t)NB * NP * NC;
  _Float16* BloT = BhiT + (size_t)NB * NP * NC;

  // 1-2: fused mean + raw split, then MFMA syrk cov
  meansplit_kernel<<<2 * NB * NC, 256, 0, stream>>>(content, style, mean, Czh, Czl);
  cov_mfma_kernel<<<dim3(10, KSPLIT, NM), 256, 0, stream>>>(Czh, Czl, pcov);
  cov_reduce_kernel<<<NM * NC * NC / 256, 256, 0, stream>>>(pcov, cov);

  // 3-4: Newton-Schulz inverse/forward sqrt (R16: fp32, Gershgorin-scaled,
  //      symmetric upper-tri tiles only)
  bound_init_kernel<<<NM, 256, 0, stream>>>(cov, Y0, Z0, scaleArr);
  float *Ya = Y0, *Za = Z0, *Yb = Y1, *Zb = Z1;
  for (int it = 0; it < NS_ITERS; it++) {
    ns_t_kernel<<<dim3(NTILE8, 1, NM), 256, 0, stream>>>(Za, Ya, T);
    ns_upd_kernel<<<dim3(NTILE8, 1, NM * 2), 256, 0, stream>>>(Ya, Za, T, Yb, Zb);
    float* tmp;
    tmp = Ya; Ya = Yb; Yb = tmp;
    tmp = Za; Za = Zb; Zb = tmp;
  }
  finalize_kernel<<<dim3(NB * NC * NC / 256, 3), 256, 0, stream>>>(Ya, Za, scaleArr,
                                                                   inv_c, inv_s, sqr_s);

  // 6: whiten both features, output [p][c] directly
  whiten_kernel<<<dim3(NP / 128, NC / 64, 2 * NB), 256, 0, stream>>>(
      content, style, mean, inv_c, inv_s, ncwT, nswT);

  // 7: fused fp16 split + style ssq (row-wise), then knorm box
  split_kernel<<<dim3(NP / 4, 1, 2 * NB), 256, 0, stream>>>(ncwT, nswT,
                                                            BhiT, BloT, AhiT, AloT, ssq);
  rknorm_kernel<<<NB * NP / 256, 256, 0, stream>>>(ssq, rk);

  // 8-9: zero packed argmax keys, then per batch: D = A B^T (MFMA fp16
  //      3-term), score with fused atomicMax argmax
  hipMemsetAsync(packed, 0, (size_t)NB * NP * sizeof(unsigned long long), stream);
  for (int b = 0; b < NB; b++) {
    dmat_kernel<<<dim3(NP / 128, NP / 128), 256, 0, stream>>>(AhiT, AloT, BhiT, BloT, Dbuf, b);
    score_kernel<<<dim3(NP / 256, NSLAB), 256, 0, stream>>>(Dbuf, rk, packed, b);
  }

  // 11: reassembly (gather form) straight from nswT, unpacking argmax keys
  reassemble_kernel<<<NB * NP, 256, 0, stream>>>(nswT, packed, reass);

  // 12: coloring straight into d_out (style_strength == 1.0)
  coloring_kernel<<<dim3(NC / 64, NP / 64, NB), 256, 0, stream>>>(sqr_s, reass, mean, out);
}